// Round 11
// baseline (353.062 us; speedup 1.0000x reference)
//
#include <hip/hip_runtime.h>
#include <math.h>

#define B_ 2
#define L_ 2048
#define E_ 2048
#define HQ 16
#define HKV 2
#define DH 128

typedef unsigned short u16;
typedef unsigned int u32;
typedef __attribute__((ext_vector_type(8))) short short8;
typedef __attribute__((ext_vector_type(4))) float f32x4;
typedef __attribute__((ext_vector_type(16))) float f32x16;
typedef __attribute__((ext_vector_type(4))) u32 u32x4;

static __device__ __forceinline__ u16 f2bf(float f) {
  unsigned int u = __float_as_uint(f);
  unsigned int r = (u + 0x7fffu + ((u >> 16) & 1u)) >> 16;
  return (u16)r;
}
static __device__ __forceinline__ float bf2f(u16 v) {
  return __uint_as_float(((u32)v) << 16);
}

static __device__ __forceinline__ u32 cvt_pk_bf16(float lo, float hi) {
  u32 r;
  asm volatile("v_cvt_pk_bf16_f32 %0, %1, %2" : "=v"(r) : "v"(lo), "v"(hi));
  return r;
}
// swaps a's upper-half lanes with b's lower-half lanes (gfx950).
static __device__ __forceinline__ void permswap(u32& a, u32& b) {
  asm volatile("v_permlane32_swap_b32 %0, %1" : "+v"(a), "+v"(b));
}

#define GLB(p) ((const __attribute__((address_space(1))) void*)(p))
#define LDS(p) ((__attribute__((address_space(3))) void*)(p))

// ---------------------------------------------------------------------------
// fp32 -> bf16 convert
// ---------------------------------------------------------------------------
__global__ void cvt_bf16_kernel(const float* __restrict__ in,
                                u16* __restrict__ out, int n) {
  int i = (blockIdx.x * 256 + threadIdx.x) * 8;
  if (i >= n) return;
  float4 a = *reinterpret_cast<const float4*>(in + i);
  float4 b = *reinterpret_cast<const float4*>(in + i + 4);
  short8 r;
  r[0] = (short)f2bf(a.x); r[1] = (short)f2bf(a.y);
  r[2] = (short)f2bf(a.z); r[3] = (short)f2bf(a.w);
  r[4] = (short)f2bf(b.x); r[5] = (short)f2bf(b.y);
  r[6] = (short)f2bf(b.z); r[7] = (short)f2bf(b.w);
  *reinterpret_cast<short8*>(out + i) = r;
}

// ---------------------------------------------------------------------------
// RoPE table
// ---------------------------------------------------------------------------
__global__ void rope_tab_kernel(float* __restrict__ ctab, float* __restrict__ stab) {
  int idx = blockIdx.x * 256 + threadIdx.x;
  if (idx >= L_ * (DH / 2)) return;
  int pos = idx >> 6;
  int f = idx & 63;
  float inv_freq = powf(10000.0f, -(float)f * (1.0f / 64.0f));
  float ang = (float)pos * inv_freq;
  float s, c;
  sincosf(ang, &s, &c);
  ctab[idx] = c;
  stab[idx] = s;
}

// ---------------------------------------------------------------------------
// RoPE apply from bf16 fused-qkv buffer -> bf16 head-major buffer
// ---------------------------------------------------------------------------
__global__ void rope_convert_kernel(const u16* __restrict__ in,
                                    u16* __restrict__ outb,
                                    const float* __restrict__ ctab,
                                    const float* __restrict__ stab,
                                    int H, int rowStride, int colOff,
                                    float scale, int total) {
  int idx = blockIdx.x * 256 + threadIdx.x;
  if (idx >= total) return;
  int f = idx & 63;
  int row = idx >> 6;
  int h = row % H;
  int bl = row / H;
  int l = bl & (L_ - 1);
  size_t sbase = (size_t)bl * rowStride + colOff + (size_t)h * DH;
  size_t dbase = (size_t)bl * ((size_t)H * DH) + (size_t)h * DH;
  float x1 = bf2f(in[sbase + f]);
  float x2 = bf2f(in[sbase + 64 + f]);
  float c = ctab[l * 64 + f];
  float s = stab[l * 64 + f];
  outb[dbase + f]      = f2bf((x1 * c - x2 * s) * scale);
  outb[dbase + 64 + f] = f2bf((x2 * c + x1 * s) * scale);
}

// ---------------------------------------------------------------------------
// V transpose from bf16 qkv buffer: -> Vt[(b*HKV+kvh)*128+d][key]
// ---------------------------------------------------------------------------
__global__ __launch_bounds__(256) void transpose_v_kernel(
    const u16* __restrict__ v, u16* __restrict__ Vt,
    int rowStride, int colOff) {
  __shared__ u16 tile[64][68];
  const int k0 = blockIdx.x * 64;
  const int d0 = blockIdx.y * 64;
  const int bk = blockIdx.z;
  const int b = bk / HKV, kvh = bk % HKV;
#pragma unroll
  for (int i = 0; i < 4; ++i) {
    int key = i * 16 + (threadIdx.x >> 4);
    int d4 = (threadIdx.x & 15) * 4;
    *reinterpret_cast<ushort2*>(&tile[key][d4]) = *reinterpret_cast<const ushort2*>(
        &v[(size_t)(b * L_ + k0 + key) * rowStride + colOff + kvh * DH + d0 + d4]);
    *reinterpret_cast<ushort2*>(&tile[key][d4 + 2]) = *reinterpret_cast<const ushort2*>(
        &v[(size_t)(b * L_ + k0 + key) * rowStride + colOff + kvh * DH + d0 + d4 + 2]);
  }
  __syncthreads();
  const int d = threadIdx.x >> 2;
  const int kq = (threadIdx.x & 3) * 16;
  u16* orow = Vt + ((size_t)(bk * DH + d0 + d)) * L_ + k0 + kq;
#pragma unroll
  for (int j = 0; j < 16; ++j) orow[j] = tile[kq + j][d];
}

// ---------------------------------------------------------------------------
// bf16 MFMA GEMM: 128x64 tile, BK=32, 4 waves (2x2 of 64x32), slot-major
// LDS (conflict-free ds_read_b128), bijective XCD swizzle, m97-style
// global_load_lds staging. Grid must be divisible by 8.
// ---------------------------------------------------------------------------
#define GBM 128
#define GBN 64
#define GBK 32

template <bool BF16OUT>
__global__ __launch_bounds__(256) void gemm_bf16_kernel(
    const u16* __restrict__ A, const u16* __restrict__ W,
    const float* __restrict__ bias, void* __restrict__ Cv,
    int M, int N, int K)
{
  // slot-major: chunk = slot*ROWS + row ; each chunk = 16 B (8 bf16)
  __shared__ u16 As[GBM * GBK];   // 512 chunks, 8 KB
  __shared__ u16 Bs[GBN * GBK];   // 256 chunks, 4 KB

  const int tid = threadIdx.x;
  const int wave = tid >> 6;
  const int lane = tid & 63;
  const int lr = lane & 15;
  const int lg = lane >> 4;

  // bijective XCD-chunked swizzle (nwg % 8 == 0)
  const int nwg = gridDim.x;
  const int qch = nwg >> 3;
  const int bid = blockIdx.x;
  const int wgid = (bid & 7) * qch + (bid >> 3);
  const int nx = N / GBN;
  const int bm = (wgid / nx) * GBM;
  const int bn = (wgid % nx) * GBN;

  const int wm = (wave >> 1) * 64;
  const int wn = (wave & 1) * 32;

  f32x4 acc[4][2];
#pragma unroll
  for (int i = 0; i < 4; ++i)
#pragma unroll
    for (int j = 0; j < 2; ++j) acc[i][j] = (f32x4){0.f, 0.f, 0.f, 0.f};

  // staging source addresses (per-lane), dest = linear chunk = wave*64+lane
  const int cA0 = wave * 64 + lane;          // A chunks 0..255
  const int cA1 = 256 + cA0;                 // A chunks 256..511
  const int cB0 = cA0;                       // B chunks 0..255
  const u16* gA0 = A + (size_t)(bm + (cA0 & 127)) * K + (cA0 >> 7) * 8;
  const u16* gA1 = A + (size_t)(bm + (cA1 & 127)) * K + (cA1 >> 7) * 8;
  const u16* gB0 = W + (size_t)(bn + (cB0 & 63)) * K + (cB0 >> 6) * 8;
  u16* lA0 = &As[(wave * 64) * 8];
  u16* lA1 = &As[(256 + wave * 64) * 8];
  u16* lB0 = &Bs[(wave * 64) * 8];

  for (int k0 = 0; k0 < K; k0 += GBK) {
    __syncthreads();
    __builtin_amdgcn_global_load_lds(GLB(gA0 + k0), LDS(lA0), 16, 0, 0);
    __builtin_amdgcn_global_load_lds(GLB(gA1 + k0), LDS(lA1), 16, 0, 0);
    __builtin_amdgcn_global_load_lds(GLB(gB0 + k0), LDS(lB0), 16, 0, 0);
    __syncthreads();

    short8 af[4], bf[2];
#pragma unroll
    for (int mi = 0; mi < 4; ++mi)
      af[mi] = *reinterpret_cast<const short8*>(&As[(lg * 128 + wm + mi * 16 + lr) * 8]);
#pragma unroll
    for (int ni = 0; ni < 2; ++ni)
      bf[ni] = *reinterpret_cast<const short8*>(&Bs[(lg * 64 + wn + ni * 16 + lr) * 8]);
#pragma unroll
    for (int mi = 0; mi < 4; ++mi)
#pragma unroll
      for (int ni = 0; ni < 2; ++ni)
        acc[mi][ni] = __builtin_amdgcn_mfma_f32_16x16x32_bf16(af[mi], bf[ni], acc[mi][ni], 0, 0, 0);
  }

#pragma unroll
  for (int ni = 0; ni < 2; ++ni) {
    int col = bn + wn + ni * 16 + lr;
    float bv = (bias != nullptr) ? bias[col] : 0.f;
#pragma unroll
    for (int mi = 0; mi < 4; ++mi) {
#pragma unroll
      for (int r = 0; r < 4; ++r) {
        int row = bm + wm + mi * 16 + lg * 4 + r;
        float val = acc[mi][ni][r] + bv;
        if constexpr (BF16OUT)
          ((u16*)Cv)[(size_t)row * N + col] = f2bf(val);
        else
          ((float*)Cv)[(size_t)row * N + col] = val;
      }
    }
  }
}

// ---------------------------------------------------------------------------
// Flash attention, LDS K/V shared by 4 heads, counted-vmcnt pipeline (T3/T4).
// Block = 4 waves (256 thr) = 4 heads x ONE 32-row q-tile. Grid 512 = 2
// blocks/CU; blocks i and i+256 carry tiles 63-u and u (65 steps per CU).
// ---------------------------------------------------------------------------
__device__ __forceinline__ void head_step(
    const short8 qB[8], const short8 kc[8], const short8 vv[8],
    int j0, int q0, int l5, int hi, float* cbufw,
    f32x16 O[4], float& mrun, float& lrun)
{
  f32x16 accl, acch;
#pragma unroll
  for (int r = 0; r < 16; ++r) { accl[r] = 0.f; acch[r] = 0.f; }
#pragma unroll
  for (int s = 0; s < 4; ++s)
    accl = __builtin_amdgcn_mfma_f32_32x32x16_bf16(kc[s], qB[s], accl, 0, 0, 0);
#pragma unroll
  for (int s = 4; s < 8; ++s)
    acch = __builtin_amdgcn_mfma_f32_32x32x16_bf16(kc[s], qB[s], acch, 0, 0, 0);

  float S[16];
#pragma unroll
  for (int r = 0; r < 16; ++r) S[r] = accl[r] + acch[r];

  if (j0 == q0) {
#pragma unroll
    for (int r = 0; r < 16; ++r) {
      int crow = (r & 3) + 8 * (r >> 2) + 4 * hi;
      if (crow > l5) S[r] = -INFINITY;
    }
  }

  float t8[8], t4[4], t2[2];
#pragma unroll
  for (int r = 0; r < 8; ++r) t8[r] = fmaxf(S[2 * r], S[2 * r + 1]);
#pragma unroll
  for (int r = 0; r < 4; ++r) t4[r] = fmaxf(t8[2 * r], t8[2 * r + 1]);
  t2[0] = fmaxf(t4[0], t4[1]); t2[1] = fmaxf(t4[2], t4[3]);
  float pmax = fmaxf(t2[0], t2[1]);
  pmax = fmaxf(pmax, __shfl_xor(pmax, 32));

  if (__any(pmax > mrun + 8.0f)) {
    float mnew = fmaxf(mrun, pmax);
    float corr = __expf(mrun - mnew);
    mrun = mnew;
    lrun *= corr;
    if (hi == 0) cbufw[l5] = corr;
    float4 cr[4];
#pragma unroll
    for (int g = 0; g < 4; ++g)
      cr[g] = *reinterpret_cast<const float4*>(&cbufw[8 * g + 4 * hi]);
#pragma unroll
    for (int n = 0; n < 4; ++n)
#pragma unroll
      for (int r = 0; r < 16; ++r)
        O[n][r] *= (&cr[r >> 2].x)[r & 3];
  }

  float p[16];
#pragma unroll
  for (int r = 0; r < 16; ++r) p[r] = __expf(S[r] - mrun);
#pragma unroll
  for (int r = 0; r < 8; ++r) t8[r] = p[2 * r] + p[2 * r + 1];
#pragma unroll
  for (int r = 0; r < 4; ++r) t4[r] = t8[2 * r] + t8[2 * r + 1];
  t2[0] = t4[0] + t4[1]; t2[1] = t4[2] + t4[3];
  lrun += t2[0] + t2[1];

  u32 w[8];
#pragma unroll
  for (int t = 0; t < 8; ++t) w[t] = cvt_pk_bf16(p[2 * t], p[2 * t + 1]);
  permswap(w[0], w[2]); permswap(w[1], w[3]);
  permswap(w[4], w[6]); permswap(w[5], w[7]);
  short8 pa0 = __builtin_bit_cast(short8, (u32x4){w[0], w[1], w[2], w[3]});
  short8 pa1 = __builtin_bit_cast(short8, (u32x4){w[4], w[5], w[6], w[7]});

#pragma unroll
  for (int n = 0; n < 4; ++n) {
    O[n] = __builtin_amdgcn_mfma_f32_32x32x16_bf16(pa0, vv[n * 2 + 0], O[n], 0, 0, 0);
    O[n] = __builtin_amdgcn_mfma_f32_32x32x16_bf16(pa1, vv[n * 2 + 1], O[n], 0, 0, 0);
  }
}

__device__ __forceinline__ void head_epilogue(
    const f32x16 O[4], float lrun, int l5, int hi, float* cbufw,
    u16* __restrict__ obase)
{
  float ltot = lrun + __shfl_xor(lrun, 32);
  if (hi == 0) cbufw[l5] = ltot;
  float4 lv[4];
#pragma unroll
  for (int gg = 0; gg < 4; ++gg)
    lv[gg] = *reinterpret_cast<const float4*>(&cbufw[8 * gg + 4 * hi]);
#pragma unroll
  for (int r = 0; r < 16; ++r) {
    int crow = (r & 3) + 8 * (r >> 2) + 4 * hi;
    float inv = __builtin_amdgcn_rcpf((&lv[r >> 2].x)[r & 3]);
    u16* orow = obase + (size_t)crow * (HQ * DH) + l5;
#pragma unroll
    for (int n = 0; n < 4; ++n)
      orow[n * 32] = f2bf(O[n][r] * inv);
  }
}

__global__ __launch_bounds__(256, 2) void flash_attn_pipe_kernel(
    const u16* __restrict__ Qb, const u16* __restrict__ Kb,
    const u16* __restrict__ Vt, u16* __restrict__ ab)
{
  const int tid = threadIdx.x;
  const int wave = tid >> 6;
  const int lane = tid & 63;
  const int l5 = lane & 31;
  const int hi = lane >> 5;

  const int bid = blockIdx.x;
  const int half = bid >> 8;
  const int u = (bid >> 3) & 31;
  const int x = bid & 7;
  const int c = x >> 1;
  const int hh = x & 1;
  const int b = c >> 1, kvh = c & 1;
  const int h = kvh * 8 + hh * 4 + wave;
  const int t = half ? u : (63 - u);
  const int q0 = 32 * t;
  const int nst = t + 1;
  const int bk = b * HKV + kvh;

  __shared__ u16 Ks[2][32 * 128];
  __shared__ u16 Vs[2][128 * 32];
  __shared__ __align__(16) float cbuf[4][32];
  float* cbufw = cbuf[wave];

  const u16* Kg = Kb + (size_t)(b * L_) * (HKV * DH) + kvh * DH;
  const u16* Vg = Vt + (size_t)(bk * DH) * L_;

  auto stage = [&](int s) {
    const int buf = s & 1;
    const int j0 = s * 32;
#pragma unroll
    for (int q = 0; q < 2; ++q) {
      int cnk = (q * 4 + wave) * 64 + lane;
      int key = cnk >> 4, slot = cnk & 15;
      const u16* src = Kg + (size_t)(j0 + key) * (HKV * DH) + (slot ^ (key & 7)) * 8;
      __builtin_amdgcn_global_load_lds(GLB(src), LDS(&Ks[buf][(q * 4 + wave) * 64 * 8]), 16, 0, 0);
    }
#pragma unroll
    for (int q = 0; q < 2; ++q) {
      int cnk = (q * 4 + wave) * 64 + lane;
      int d = cnk >> 2, slot = cnk & 3;
      const u16* src = Vg + (size_t)d * L_ + j0 + (slot ^ ((d >> 1) & 3)) * 8;
      __builtin_amdgcn_global_load_lds(GLB(src), LDS(&Vs[buf][(q * 4 + wave) * 64 * 8]), 16, 0, 0);
    }
  };

  const u16* qrow = Qb + ((size_t)(b * L_ + q0 + l5)) * (HQ * DH) + h * DH + hi * 8;
  short8 qB[8];
#pragma unroll
  for (int ss = 0; ss < 8; ++ss)
    qB[ss] = *reinterpret_cast<const short8*>(qrow + ss * 16);

  f32x16 O[4];
#pragma unroll
  for (int n = 0; n < 4; ++n)
#pragma unroll
    for (int r = 0; r < 16; ++r) O[n][r] = 0.f;
  float mrun = -INFINITY, lrun = 0.f;

  stage(0);
  if (nst > 1) stage(1);

#pragma unroll 1
  for (int s = 0; s < nst; ++s) {
    if (s + 1 < nst) { asm volatile("s_waitcnt vmcnt(4)" ::: "memory"); }
    else             { asm volatile("s_waitcnt vmcnt(0)" ::: "memory"); }
    __builtin_amdgcn_s_barrier();
    __builtin_amdgcn_sched_barrier(0);

    const int cur = s & 1;
    short8 kc[8], vv[8];
#pragma unroll
    for (int ss = 0; ss < 8; ++ss) {
      int slot = (2 * ss + hi) ^ (l5 & 7);
      kc[ss] = *reinterpret_cast<const short8*>(&Ks[cur][l5 * 128 + slot * 8]);
    }
#pragma unroll
    for (int n = 0; n < 4; ++n) {
#pragma unroll
      for (int cc = 0; cc < 2; ++cc) {
        int d = n * 32 + l5;
        int slot = (cc * 2 + hi) ^ ((d >> 1) & 3);
        vv[n * 2 + cc] = *reinterpret_cast<const short8*>(&Vs[cur][d * 32 + slot * 8]);
      }
    }
    asm volatile("s_waitcnt lgkmcnt(0)" ::: "memory");
    __builtin_amdgcn_sched_barrier(0);
    __builtin_amdgcn_s_barrier();
    if (s + 2 < nst) stage(s + 2);

    head_step(qB, kc, vv, s * 32, q0, l5, hi, cbufw, O, mrun, lrun);
  }

  u16* obase = ab + (size_t)(b * L_ + q0) * (HQ * DH) + h * DH;
  head_epilogue(O, lrun, l5, hi, cbufw, obase);
}

// ---------------------------------------------------------------------------
// launch
// ---------------------------------------------------------------------------
extern "C" void kernel_launch(void* const* d_in, const int* in_sizes, int n_in,
                              void* d_out, int out_size, void* d_ws, size_t ws_size,
                              hipStream_t stream) {
  const float* x  = (const float*)d_in[0];
  const float* wq = (const float*)d_in[1];
  const float* wk = (const float*)d_in[2];
  const float* wv = (const float*)d_in[3];
  const float* wo = (const float*)d_in[4];
  const float* bq = (const float*)d_in[5];
  const float* bk = (const float*)d_in[6];
  const float* bv = (const float*)d_in[7];
  float* out = (float*)d_out;

  const int M = B_ * L_;
  const int NQKV = HQ * DH + 2 * HKV * DH;  // 2560
  const size_t QN = (size_t)B_ * L_ * HQ * DH;
  const size_t KN = (size_t)B_ * L_ * HKV * DH;
  const size_t TN = (size_t)L_ * (DH / 2);

  float* ws = (float*)d_ws;
  float* ct   = ws;
  float* st   = ct + TN;
  float* bqkv = st + TN;
  u16* qkvb   = (u16*)(bqkv + 2560);        // bf16 QKV projection output
  u16* xb     = qkvb + (size_t)M * NQKV;
  u16* wqkvb  = xb + (size_t)M * E_;
  u16* Qbf    = wqkvb + (size_t)NQKV * E_;
  u16* Kbf    = Qbf + QN;
  u16* Vt     = Kbf + KN;
  u16* ab     = qkvb;   // alias: qkvb dead after rope/transpose
  u16* wob    = Qbf;    // alias: Qbf dead after attention

  const float scale = 0.08838834764831845f;

  rope_tab_kernel<<<(L_ * (DH / 2) + 255) / 256, 256, 0, stream>>>(ct, st);

  cvt_bf16_kernel<<<(int)(QN / 8 / 256), 256, 0, stream>>>(x, xb, (int)QN);
  cvt_bf16_kernel<<<(HQ * DH * E_) / 8 / 256, 256, 0, stream>>>(wq, wqkvb, HQ * DH * E_);
  cvt_bf16_kernel<<<(HKV * DH * E_) / 8 / 256, 256, 0, stream>>>(
      wk, wqkvb + (size_t)(HQ * DH) * E_, HKV * DH * E_);
  cvt_bf16_kernel<<<(HKV * DH * E_) / 8 / 256, 256, 0, stream>>>(
      wv, wqkvb + (size_t)(HQ * DH + HKV * DH) * E_, HKV * DH * E_);

  hipMemcpyAsync(bqkv, bq, (size_t)HQ * DH * 4, hipMemcpyDeviceToDevice, stream);
  hipMemcpyAsync(bqkv + HQ * DH, bk, (size_t)HKV * DH * 4, hipMemcpyDeviceToDevice, stream);
  hipMemcpyAsync(bqkv + HQ * DH + HKV * DH, bv, (size_t)HKV * DH * 4, hipMemcpyDeviceToDevice, stream);

  // fused QKV projection: grid 40*32 = 1280 blocks (5/CU)
  gemm_bf16_kernel<true><<<dim3((NQKV / GBN) * (M / GBM)), 256, 0, stream>>>(
      xb, wqkvb, bqkv, qkvb, M, NQKV, E_);

  {
    int totq = B_ * L_ * HQ * 64;
    rope_convert_kernel<<<(totq + 255) / 256, 256, 0, stream>>>(
        qkvb, Qbf, ct, st, HQ, NQKV, 0, scale, totq);
    int totk = B_ * L_ * HKV * 64;
    rope_convert_kernel<<<(totk + 255) / 256, 256, 0, stream>>>(
        qkvb, Kbf, ct, st, HKV, NQKV, HQ * DH, 1.0f, totk);
  }
  transpose_v_kernel<<<dim3(L_ / 64, DH / 64, B_ * HKV), 256, 0, stream>>>(
      qkvb, Vt, NQKV, HQ * DH + HKV * DH);

  flash_attn_pipe_kernel<<<dim3(512), 256, 0, stream>>>(Qbf, Kbf, Vt, ab);

  cvt_bf16_kernel<<<(E_ * E_) / 8 / 256, 256, 0, stream>>>(wo, wob, E_ * E_);
  // O-projection: grid 32*32 = 1024 blocks (4/CU)
  gemm_bf16_kernel<false><<<dim3((E_ / GBN) * (M / GBM)), 256, 0, stream>>>(
      ab, wob, nullptr, out, M, E_, E_);
}

// Round 12
// 289.901 us; speedup vs baseline: 1.2179x; 1.2179x over previous
//
#include <hip/hip_runtime.h>
#include <math.h>

#define B_ 2
#define L_ 2048
#define E_ 2048
#define HQ 16
#define HKV 2
#define DH 128

typedef unsigned short u16;
typedef unsigned int u32;
typedef __attribute__((ext_vector_type(8))) short short8;
typedef __attribute__((ext_vector_type(4))) float f32x4;
typedef __attribute__((ext_vector_type(16))) float f32x16;
typedef __attribute__((ext_vector_type(4))) u32 u32x4;

static __device__ __forceinline__ u16 f2bf(float f) {
  unsigned int u = __float_as_uint(f);
  unsigned int r = (u + 0x7fffu + ((u >> 16) & 1u)) >> 16;
  return (u16)r;
}
static __device__ __forceinline__ float bf2f(u16 v) {
  return __uint_as_float(((u32)v) << 16);
}

static __device__ __forceinline__ u32 cvt_pk_bf16(float lo, float hi) {
  u32 r;
  asm volatile("v_cvt_pk_bf16_f32 %0, %1, %2" : "=v"(r) : "v"(lo), "v"(hi));
  return r;
}
// swaps a's upper-half lanes with b's lower-half lanes (gfx950).
static __device__ __forceinline__ void permswap(u32& a, u32& b) {
  asm volatile("v_permlane32_swap_b32 %0, %1" : "+v"(a), "+v"(b));
}

#define GLB(p) ((const __attribute__((address_space(1))) void*)(p))
#define LDS(p) ((__attribute__((address_space(3))) void*)(p))

// ---------------------------------------------------------------------------
// fp32 -> bf16 convert
// ---------------------------------------------------------------------------
__global__ void cvt_bf16_kernel(const float* __restrict__ in,
                                u16* __restrict__ out, int n) {
  int i = (blockIdx.x * 256 + threadIdx.x) * 8;
  if (i >= n) return;
  float4 a = *reinterpret_cast<const float4*>(in + i);
  float4 b = *reinterpret_cast<const float4*>(in + i + 4);
  short8 r;
  r[0] = (short)f2bf(a.x); r[1] = (short)f2bf(a.y);
  r[2] = (short)f2bf(a.z); r[3] = (short)f2bf(a.w);
  r[4] = (short)f2bf(b.x); r[5] = (short)f2bf(b.y);
  r[6] = (short)f2bf(b.z); r[7] = (short)f2bf(b.w);
  *reinterpret_cast<short8*>(out + i) = r;
}

// ---------------------------------------------------------------------------
// RoPE table
// ---------------------------------------------------------------------------
__global__ void rope_tab_kernel(float* __restrict__ ctab, float* __restrict__ stab) {
  int idx = blockIdx.x * 256 + threadIdx.x;
  if (idx >= L_ * (DH / 2)) return;
  int pos = idx >> 6;
  int f = idx & 63;
  float inv_freq = powf(10000.0f, -(float)f * (1.0f / 64.0f));
  float ang = (float)pos * inv_freq;
  float s, c;
  sincosf(ang, &s, &c);
  ctab[idx] = c;
  stab[idx] = s;
}

// ---------------------------------------------------------------------------
// RoPE apply from bf16 fused-qkv buffer -> bf16 head-major buffer
// ---------------------------------------------------------------------------
__global__ void rope_convert_kernel(const u16* __restrict__ in,
                                    u16* __restrict__ outb,
                                    const float* __restrict__ ctab,
                                    const float* __restrict__ stab,
                                    int H, int rowStride, int colOff,
                                    float scale, int total) {
  int idx = blockIdx.x * 256 + threadIdx.x;
  if (idx >= total) return;
  int f = idx & 63;
  int row = idx >> 6;
  int h = row % H;
  int bl = row / H;
  int l = bl & (L_ - 1);
  size_t sbase = (size_t)bl * rowStride + colOff + (size_t)h * DH;
  size_t dbase = (size_t)bl * ((size_t)H * DH) + (size_t)h * DH;
  float x1 = bf2f(in[sbase + f]);
  float x2 = bf2f(in[sbase + 64 + f]);
  float c = ctab[l * 64 + f];
  float s = stab[l * 64 + f];
  outb[dbase + f]      = f2bf((x1 * c - x2 * s) * scale);
  outb[dbase + 64 + f] = f2bf((x2 * c + x1 * s) * scale);
}

// ---------------------------------------------------------------------------
// V transpose from bf16 qkv buffer: -> Vt[(b*HKV+kvh)*128+d][key]
// ---------------------------------------------------------------------------
__global__ __launch_bounds__(256) void transpose_v_kernel(
    const u16* __restrict__ v, u16* __restrict__ Vt,
    int rowStride, int colOff) {
  __shared__ u16 tile[64][68];
  const int k0 = blockIdx.x * 64;
  const int d0 = blockIdx.y * 64;
  const int bk = blockIdx.z;
  const int b = bk / HKV, kvh = bk % HKV;
#pragma unroll
  for (int i = 0; i < 4; ++i) {
    int key = i * 16 + (threadIdx.x >> 4);
    int d4 = (threadIdx.x & 15) * 4;
    *reinterpret_cast<ushort2*>(&tile[key][d4]) = *reinterpret_cast<const ushort2*>(
        &v[(size_t)(b * L_ + k0 + key) * rowStride + colOff + kvh * DH + d0 + d4]);
    *reinterpret_cast<ushort2*>(&tile[key][d4 + 2]) = *reinterpret_cast<const ushort2*>(
        &v[(size_t)(b * L_ + k0 + key) * rowStride + colOff + kvh * DH + d0 + d4 + 2]);
  }
  __syncthreads();
  const int d = threadIdx.x >> 2;
  const int kq = (threadIdx.x & 3) * 16;
  u16* orow = Vt + ((size_t)(bk * DH + d0 + d)) * L_ + k0 + kq;
#pragma unroll
  for (int j = 0; j < 16; ++j) orow[j] = tile[kq + j][d];
}

// ---------------------------------------------------------------------------
// bf16 MFMA GEMM: 128x128 tile, BK=32, double-buffered LDS, counted-vmcnt
// pipeline (T3/T4-minimal, proven on attention R9). Slot-major LDS
// (conflict-free, proven R11) + bijective XCD swizzle. Grid % 8 == 0.
// ---------------------------------------------------------------------------
#define GBM 128
#define GBN 128
#define GBK 32

template <bool BF16OUT>
__global__ __launch_bounds__(256, 2) void gemm_bf16_kernel(
    const u16* __restrict__ A, const u16* __restrict__ W,
    const float* __restrict__ bias, void* __restrict__ Cv,
    int M, int N, int K)
{
  // slot-major chunks: chunk = slot*128 + row, each 16 B (8 bf16), slot=k/8
  __shared__ u16 As[2][GBM * GBK];   // 8 KB per buffer
  __shared__ u16 Bs[2][GBN * GBK];

  const int tid = threadIdx.x;
  const int wave = tid >> 6;
  const int lane = tid & 63;
  const int lr = lane & 15;
  const int lg = lane >> 4;

  // bijective XCD-chunked swizzle (nwg % 8 == 0)
  const int nwg = gridDim.x;
  const int qch = nwg >> 3;
  const int bid = blockIdx.x;
  const int wgid = (bid & 7) * qch + (bid >> 3);
  const int nx = N / GBN;
  const int bm = (wgid / nx) * GBM;
  const int bn = (wgid % nx) * GBN;

  const int wm = (wave >> 1) * 64;
  const int wn = (wave & 1) * 64;

  f32x4 acc[4][4];
#pragma unroll
  for (int i = 0; i < 4; ++i)
#pragma unroll
    for (int j = 0; j < 4; ++j) acc[i][j] = (f32x4){0.f, 0.f, 0.f, 0.f};

  // staging: 512 chunks per matrix; thread covers chunks c0 and c1
  const int c0 = wave * 64 + lane;          // 0..255
  const int c1 = 256 + c0;                  // 256..511
  const u16* gA0 = A + (size_t)(bm + (c0 & 127)) * K + (c0 >> 7) * 8;
  const u16* gA1 = A + (size_t)(bm + (c1 & 127)) * K + (c1 >> 7) * 8;
  const u16* gB0 = W + (size_t)(bn + (c0 & 127)) * K + (c0 >> 7) * 8;
  const u16* gB1 = W + (size_t)(bn + (c1 & 127)) * K + (c1 >> 7) * 8;

  const int nk = K / GBK;
  auto stage = [&](int s) {
    const int buf = s & 1;
    const int k0 = s * GBK;
    __builtin_amdgcn_global_load_lds(GLB(gA0 + k0), LDS(&As[buf][(wave * 64) * 8]), 16, 0, 0);
    __builtin_amdgcn_global_load_lds(GLB(gA1 + k0), LDS(&As[buf][(256 + wave * 64) * 8]), 16, 0, 0);
    __builtin_amdgcn_global_load_lds(GLB(gB0 + k0), LDS(&Bs[buf][(wave * 64) * 8]), 16, 0, 0);
    __builtin_amdgcn_global_load_lds(GLB(gB1 + k0), LDS(&Bs[buf][(256 + wave * 64) * 8]), 16, 0, 0);
  };

  stage(0);
  stage(1);

#pragma unroll 1
  for (int s = 0; s < nk; ++s) {
    if (s + 1 < nk) { asm volatile("s_waitcnt vmcnt(4)" ::: "memory"); }
    else            { asm volatile("s_waitcnt vmcnt(0)" ::: "memory"); }
    __builtin_amdgcn_s_barrier();            // (A) buf[s&1] landed for all waves
    __builtin_amdgcn_sched_barrier(0);

    const int cur = s & 1;
    short8 af[4], bf[4];
#pragma unroll
    for (int mi = 0; mi < 4; ++mi)
      af[mi] = *reinterpret_cast<const short8*>(&As[cur][(lg * 128 + wm + mi * 16 + lr) * 8]);
#pragma unroll
    for (int ni = 0; ni < 4; ++ni)
      bf[ni] = *reinterpret_cast<const short8*>(&Bs[cur][(lg * 128 + wn + ni * 16 + lr) * 8]);
    asm volatile("s_waitcnt lgkmcnt(0)" ::: "memory");
    __builtin_amdgcn_sched_barrier(0);
    __builtin_amdgcn_s_barrier();            // (B) all waves done reading buf[cur]
    if (s + 2 < nk) stage(s + 2);            // overwrite buf[cur] for step s+2

#pragma unroll
    for (int mi = 0; mi < 4; ++mi)
#pragma unroll
      for (int ni = 0; ni < 4; ++ni)
        acc[mi][ni] = __builtin_amdgcn_mfma_f32_16x16x32_bf16(af[mi], bf[ni], acc[mi][ni], 0, 0, 0);
  }

#pragma unroll
  for (int ni = 0; ni < 4; ++ni) {
    int col = bn + wn + ni * 16 + lr;
    float bv = (bias != nullptr) ? bias[col] : 0.f;
#pragma unroll
    for (int mi = 0; mi < 4; ++mi) {
#pragma unroll
      for (int r = 0; r < 4; ++r) {
        int row = bm + wm + mi * 16 + lg * 4 + r;
        float val = acc[mi][ni][r] + bv;
        if constexpr (BF16OUT)
          ((u16*)Cv)[(size_t)row * N + col] = f2bf(val);
        else
          ((float*)Cv)[(size_t)row * N + col] = val;
      }
    }
  }
}

// ---------------------------------------------------------------------------
// Flash attention, LDS K/V shared by 4 heads, counted-vmcnt pipeline (T3/T4).
// Block = 4 waves (256 thr) = 4 heads x ONE 32-row q-tile. Grid 512 = 2
// blocks/CU; blocks i and i+256 carry tiles 63-u and u (65 steps per CU).
// ---------------------------------------------------------------------------
__device__ __forceinline__ void head_step(
    const short8 qB[8], const short8 kc[8], const short8 vv[8],
    int j0, int q0, int l5, int hi, float* cbufw,
    f32x16 O[4], float& mrun, float& lrun)
{
  f32x16 accl, acch;
#pragma unroll
  for (int r = 0; r < 16; ++r) { accl[r] = 0.f; acch[r] = 0.f; }
#pragma unroll
  for (int s = 0; s < 4; ++s)
    accl = __builtin_amdgcn_mfma_f32_32x32x16_bf16(kc[s], qB[s], accl, 0, 0, 0);
#pragma unroll
  for (int s = 4; s < 8; ++s)
    acch = __builtin_amdgcn_mfma_f32_32x32x16_bf16(kc[s], qB[s], acch, 0, 0, 0);

  float S[16];
#pragma unroll
  for (int r = 0; r < 16; ++r) S[r] = accl[r] + acch[r];

  if (j0 == q0) {
#pragma unroll
    for (int r = 0; r < 16; ++r) {
      int crow = (r & 3) + 8 * (r >> 2) + 4 * hi;
      if (crow > l5) S[r] = -INFINITY;
    }
  }

  float t8[8], t4[4], t2[2];
#pragma unroll
  for (int r = 0; r < 8; ++r) t8[r] = fmaxf(S[2 * r], S[2 * r + 1]);
#pragma unroll
  for (int r = 0; r < 4; ++r) t4[r] = fmaxf(t8[2 * r], t8[2 * r + 1]);
  t2[0] = fmaxf(t4[0], t4[1]); t2[1] = fmaxf(t4[2], t4[3]);
  float pmax = fmaxf(t2[0], t2[1]);
  pmax = fmaxf(pmax, __shfl_xor(pmax, 32));

  if (__any(pmax > mrun + 8.0f)) {
    float mnew = fmaxf(mrun, pmax);
    float corr = __expf(mrun - mnew);
    mrun = mnew;
    lrun *= corr;
    if (hi == 0) cbufw[l5] = corr;
    float4 cr[4];
#pragma unroll
    for (int g = 0; g < 4; ++g)
      cr[g] = *reinterpret_cast<const float4*>(&cbufw[8 * g + 4 * hi]);
#pragma unroll
    for (int n = 0; n < 4; ++n)
#pragma unroll
      for (int r = 0; r < 16; ++r)
        O[n][r] *= (&cr[r >> 2].x)[r & 3];
  }

  float p[16];
#pragma unroll
  for (int r = 0; r < 16; ++r) p[r] = __expf(S[r] - mrun);
#pragma unroll
  for (int r = 0; r < 8; ++r) t8[r] = p[2 * r] + p[2 * r + 1];
#pragma unroll
  for (int r = 0; r < 4; ++r) t4[r] = t8[2 * r] + t8[2 * r + 1];
  t2[0] = t4[0] + t4[1]; t2[1] = t4[2] + t4[3];
  lrun += t2[0] + t2[1];

  u32 w[8];
#pragma unroll
  for (int t = 0; t < 8; ++t) w[t] = cvt_pk_bf16(p[2 * t], p[2 * t + 1]);
  permswap(w[0], w[2]); permswap(w[1], w[3]);
  permswap(w[4], w[6]); permswap(w[5], w[7]);
  short8 pa0 = __builtin_bit_cast(short8, (u32x4){w[0], w[1], w[2], w[3]});
  short8 pa1 = __builtin_bit_cast(short8, (u32x4){w[4], w[5], w[6], w[7]});

#pragma unroll
  for (int n = 0; n < 4; ++n) {
    O[n] = __builtin_amdgcn_mfma_f32_32x32x16_bf16(pa0, vv[n * 2 + 0], O[n], 0, 0, 0);
    O[n] = __builtin_amdgcn_mfma_f32_32x32x16_bf16(pa1, vv[n * 2 + 1], O[n], 0, 0, 0);
  }
}

__device__ __forceinline__ void head_epilogue(
    const f32x16 O[4], float lrun, int l5, int hi, float* cbufw,
    u16* __restrict__ obase)
{
  float ltot = lrun + __shfl_xor(lrun, 32);
  if (hi == 0) cbufw[l5] = ltot;
  float4 lv[4];
#pragma unroll
  for (int gg = 0; gg < 4; ++gg)
    lv[gg] = *reinterpret_cast<const float4*>(&cbufw[8 * gg + 4 * hi]);
#pragma unroll
  for (int r = 0; r < 16; ++r) {
    int crow = (r & 3) + 8 * (r >> 2) + 4 * hi;
    float inv = __builtin_amdgcn_rcpf((&lv[r >> 2].x)[r & 3]);
    u16* orow = obase + (size_t)crow * (HQ * DH) + l5;
#pragma unroll
    for (int n = 0; n < 4; ++n)
      orow[n * 32] = f2bf(O[n][r] * inv);
  }
}

__global__ __launch_bounds__(256, 2) void flash_attn_pipe_kernel(
    const u16* __restrict__ Qb, const u16* __restrict__ Kb,
    const u16* __restrict__ Vt, u16* __restrict__ ab)
{
  const int tid = threadIdx.x;
  const int wave = tid >> 6;
  const int lane = tid & 63;
  const int l5 = lane & 31;
  const int hi = lane >> 5;

  const int bid = blockIdx.x;
  const int half = bid >> 8;
  const int u = (bid >> 3) & 31;
  const int x = bid & 7;
  const int c = x >> 1;
  const int hh = x & 1;
  const int b = c >> 1, kvh = c & 1;
  const int h = kvh * 8 + hh * 4 + wave;
  const int t = half ? u : (63 - u);
  const int q0 = 32 * t;
  const int nst = t + 1;
  const int bk = b * HKV + kvh;

  __shared__ u16 Ks[2][32 * 128];
  __shared__ u16 Vs[2][128 * 32];
  __shared__ __align__(16) float cbuf[4][32];
  float* cbufw = cbuf[wave];

  const u16* Kg = Kb + (size_t)(b * L_) * (HKV * DH) + kvh * DH;
  const u16* Vg = Vt + (size_t)(bk * DH) * L_;

  auto stage = [&](int s) {
    const int buf = s & 1;
    const int j0 = s * 32;
#pragma unroll
    for (int q = 0; q < 2; ++q) {
      int cnk = (q * 4 + wave) * 64 + lane;
      int key = cnk >> 4, slot = cnk & 15;
      const u16* src = Kg + (size_t)(j0 + key) * (HKV * DH) + (slot ^ (key & 7)) * 8;
      __builtin_amdgcn_global_load_lds(GLB(src), LDS(&Ks[buf][(q * 4 + wave) * 64 * 8]), 16, 0, 0);
    }
#pragma unroll
    for (int q = 0; q < 2; ++q) {
      int cnk = (q * 4 + wave) * 64 + lane;
      int d = cnk >> 2, slot = cnk & 3;
      const u16* src = Vg + (size_t)d * L_ + j0 + (slot ^ ((d >> 1) & 3)) * 8;
      __builtin_amdgcn_global_load_lds(GLB(src), LDS(&Vs[buf][(q * 4 + wave) * 64 * 8]), 16, 0, 0);
    }
  };

  const u16* qrow = Qb + ((size_t)(b * L_ + q0 + l5)) * (HQ * DH) + h * DH + hi * 8;
  short8 qB[8];
#pragma unroll
  for (int ss = 0; ss < 8; ++ss)
    qB[ss] = *reinterpret_cast<const short8*>(qrow + ss * 16);

  f32x16 O[4];
#pragma unroll
  for (int n = 0; n < 4; ++n)
#pragma unroll
    for (int r = 0; r < 16; ++r) O[n][r] = 0.f;
  float mrun = -INFINITY, lrun = 0.f;

  stage(0);
  if (nst > 1) stage(1);

#pragma unroll 1
  for (int s = 0; s < nst; ++s) {
    if (s + 1 < nst) { asm volatile("s_waitcnt vmcnt(4)" ::: "memory"); }
    else             { asm volatile("s_waitcnt vmcnt(0)" ::: "memory"); }
    __builtin_amdgcn_s_barrier();
    __builtin_amdgcn_sched_barrier(0);

    const int cur = s & 1;
    short8 kc[8], vv[8];
#pragma unroll
    for (int ss = 0; ss < 8; ++ss) {
      int slot = (2 * ss + hi) ^ (l5 & 7);
      kc[ss] = *reinterpret_cast<const short8*>(&Ks[cur][l5 * 128 + slot * 8]);
    }
#pragma unroll
    for (int n = 0; n < 4; ++n) {
#pragma unroll
      for (int cc = 0; cc < 2; ++cc) {
        int d = n * 32 + l5;
        int slot = (cc * 2 + hi) ^ ((d >> 1) & 3);
        vv[n * 2 + cc] = *reinterpret_cast<const short8*>(&Vs[cur][d * 32 + slot * 8]);
      }
    }
    asm volatile("s_waitcnt lgkmcnt(0)" ::: "memory");
    __builtin_amdgcn_sched_barrier(0);
    __builtin_amdgcn_s_barrier();
    if (s + 2 < nst) stage(s + 2);

    head_step(qB, kc, vv, s * 32, q0, l5, hi, cbufw, O, mrun, lrun);
  }

  u16* obase = ab + (size_t)(b * L_ + q0) * (HQ * DH) + h * DH;
  head_epilogue(O, lrun, l5, hi, cbufw, obase);
}

// ---------------------------------------------------------------------------
// launch
// ---------------------------------------------------------------------------
extern "C" void kernel_launch(void* const* d_in, const int* in_sizes, int n_in,
                              void* d_out, int out_size, void* d_ws, size_t ws_size,
                              hipStream_t stream) {
  const float* x  = (const float*)d_in[0];
  const float* wq = (const float*)d_in[1];
  const float* wk = (const float*)d_in[2];
  const float* wv = (const float*)d_in[3];
  const float* wo = (const float*)d_in[4];
  const float* bq = (const float*)d_in[5];
  const float* bk = (const float*)d_in[6];
  const float* bv = (const float*)d_in[7];
  float* out = (float*)d_out;

  const int M = B_ * L_;
  const int NQKV = HQ * DH + 2 * HKV * DH;  // 2560
  const size_t QN = (size_t)B_ * L_ * HQ * DH;
  const size_t KN = (size_t)B_ * L_ * HKV * DH;
  const size_t TN = (size_t)L_ * (DH / 2);

  float* ws = (float*)d_ws;
  float* ct   = ws;
  float* st   = ct + TN;
  float* bqkv = st + TN;
  u16* qkvb   = (u16*)(bqkv + 2560);        // bf16 QKV projection output
  u16* xb     = qkvb + (size_t)M * NQKV;
  u16* wqkvb  = xb + (size_t)M * E_;
  u16* Qbf    = wqkvb + (size_t)NQKV * E_;
  u16* Kbf    = Qbf + QN;
  u16* Vt     = Kbf + KN;
  u16* ab     = qkvb;   // alias: qkvb dead after rope/transpose
  u16* wob    = Qbf;    // alias: Qbf dead after attention

  const float scale = 0.08838834764831845f;

  rope_tab_kernel<<<(L_ * (DH / 2) + 255) / 256, 256, 0, stream>>>(ct, st);

  cvt_bf16_kernel<<<(int)(QN / 8 / 256), 256, 0, stream>>>(x, xb, (int)QN);
  cvt_bf16_kernel<<<(HQ * DH * E_) / 8 / 256, 256, 0, stream>>>(wq, wqkvb, HQ * DH * E_);
  cvt_bf16_kernel<<<(HKV * DH * E_) / 8 / 256, 256, 0, stream>>>(
      wk, wqkvb + (size_t)(HQ * DH) * E_, HKV * DH * E_);
  cvt_bf16_kernel<<<(HKV * DH * E_) / 8 / 256, 256, 0, stream>>>(
      wv, wqkvb + (size_t)(HQ * DH + HKV * DH) * E_, HKV * DH * E_);

  hipMemcpyAsync(bqkv, bq, (size_t)HQ * DH * 4, hipMemcpyDeviceToDevice, stream);
  hipMemcpyAsync(bqkv + HQ * DH, bk, (size_t)HKV * DH * 4, hipMemcpyDeviceToDevice, stream);
  hipMemcpyAsync(bqkv + HQ * DH + HKV * DH, bv, (size_t)HKV * DH * 4, hipMemcpyDeviceToDevice, stream);

  // fused QKV projection: grid 20*32 = 640 blocks
  gemm_bf16_kernel<true><<<dim3((NQKV / GBN) * (M / GBM)), 256, 0, stream>>>(
      xb, wqkvb, bqkv, qkvb, M, NQKV, E_);

  {
    int totq = B_ * L_ * HQ * 64;
    rope_convert_kernel<<<(totq + 255) / 256, 256, 0, stream>>>(
        qkvb, Qbf, ct, st, HQ, NQKV, 0, scale, totq);
    int totk = B_ * L_ * HKV * 64;
    rope_convert_kernel<<<(totk + 255) / 256, 256, 0, stream>>>(
        qkvb, Kbf, ct, st, HKV, NQKV, HQ * DH, 1.0f, totk);
  }
  transpose_v_kernel<<<dim3(L_ / 64, DH / 64, B_ * HKV), 256, 0, stream>>>(
      qkvb, Vt, NQKV, HQ * DH + HKV * DH);

  flash_attn_pipe_kernel<<<dim3(512), 256, 0, stream>>>(Qbf, Kbf, Vt, ab);

  cvt_bf16_kernel<<<(E_ * E_) / 8 / 256, 256, 0, stream>>>(wo, wob, E_ * E_);
  // O-projection: grid 16*32 = 512 blocks
  gemm_bf16_kernel<false><<<dim3((E_ / GBN) * (M / GBM)), 256, 0, stream>>>(
      ab, wob, nullptr, out, M, E_, E_);
}

// Round 13
// 287.389 us; speedup vs baseline: 1.2285x; 1.0087x over previous
//
#include <hip/hip_runtime.h>
#include <math.h>

#define B_ 2
#define L_ 2048
#define E_ 2048
#define HQ 16
#define HKV 2
#define DH 128

typedef unsigned short u16;
typedef unsigned int u32;
typedef __attribute__((ext_vector_type(8))) short short8;
typedef __attribute__((ext_vector_type(4))) float f32x4;
typedef __attribute__((ext_vector_type(16))) float f32x16;
typedef __attribute__((ext_vector_type(4))) u32 u32x4;

static __device__ __forceinline__ u16 f2bf(float f) {
  unsigned int u = __float_as_uint(f);
  unsigned int r = (u + 0x7fffu + ((u >> 16) & 1u)) >> 16;
  return (u16)r;
}
static __device__ __forceinline__ float bf2f(u16 v) {
  return __uint_as_float(((u32)v) << 16);
}

static __device__ __forceinline__ u32 cvt_pk_bf16(float lo, float hi) {
  u32 r;
  asm volatile("v_cvt_pk_bf16_f32 %0, %1, %2" : "=v"(r) : "v"(lo), "v"(hi));
  return r;
}
// swaps a's upper-half lanes with b's lower-half lanes (gfx950).
static __device__ __forceinline__ void permswap(u32& a, u32& b) {
  asm volatile("v_permlane32_swap_b32 %0, %1" : "+v"(a), "+v"(b));
}

#define GLB(p) ((const __attribute__((address_space(1))) void*)(p))
#define LDS(p) ((__attribute__((address_space(3))) void*)(p))

// ---------------------------------------------------------------------------
// fp32 -> bf16 convert
// ---------------------------------------------------------------------------
__global__ void cvt_bf16_kernel(const float* __restrict__ in,
                                u16* __restrict__ out, int n) {
  int i = (blockIdx.x * 256 + threadIdx.x) * 8;
  if (i >= n) return;
  float4 a = *reinterpret_cast<const float4*>(in + i);
  float4 b = *reinterpret_cast<const float4*>(in + i + 4);
  short8 r;
  r[0] = (short)f2bf(a.x); r[1] = (short)f2bf(a.y);
  r[2] = (short)f2bf(a.z); r[3] = (short)f2bf(a.w);
  r[4] = (short)f2bf(b.x); r[5] = (short)f2bf(b.y);
  r[6] = (short)f2bf(b.z); r[7] = (short)f2bf(b.w);
  *reinterpret_cast<short8*>(out + i) = r;
}

// ---------------------------------------------------------------------------
// RoPE table
// ---------------------------------------------------------------------------
__global__ void rope_tab_kernel(float* __restrict__ ctab, float* __restrict__ stab) {
  int idx = blockIdx.x * 256 + threadIdx.x;
  if (idx >= L_ * (DH / 2)) return;
  int pos = idx >> 6;
  int f = idx & 63;
  float inv_freq = powf(10000.0f, -(float)f * (1.0f / 64.0f));
  float ang = (float)pos * inv_freq;
  float s, c;
  sincosf(ang, &s, &c);
  ctab[idx] = c;
  stab[idx] = s;
}

// ---------------------------------------------------------------------------
// RoPE apply from bf16 fused-qkv buffer -> bf16 head-major buffer
// ---------------------------------------------------------------------------
__global__ void rope_convert_kernel(const u16* __restrict__ in,
                                    u16* __restrict__ outb,
                                    const float* __restrict__ ctab,
                                    const float* __restrict__ stab,
                                    int H, int rowStride, int colOff,
                                    float scale, int total) {
  int idx = blockIdx.x * 256 + threadIdx.x;
  if (idx >= total) return;
  int f = idx & 63;
  int row = idx >> 6;
  int h = row % H;
  int bl = row / H;
  int l = bl & (L_ - 1);
  size_t sbase = (size_t)bl * rowStride + colOff + (size_t)h * DH;
  size_t dbase = (size_t)bl * ((size_t)H * DH) + (size_t)h * DH;
  float x1 = bf2f(in[sbase + f]);
  float x2 = bf2f(in[sbase + 64 + f]);
  float c = ctab[l * 64 + f];
  float s = stab[l * 64 + f];
  outb[dbase + f]      = f2bf((x1 * c - x2 * s) * scale);
  outb[dbase + 64 + f] = f2bf((x2 * c + x1 * s) * scale);
}

// ---------------------------------------------------------------------------
// V transpose from bf16 qkv buffer: -> Vt[(b*HKV+kvh)*128+d][key]
// ---------------------------------------------------------------------------
__global__ __launch_bounds__(256) void transpose_v_kernel(
    const u16* __restrict__ v, u16* __restrict__ Vt,
    int rowStride, int colOff) {
  __shared__ u16 tile[64][68];
  const int k0 = blockIdx.x * 64;
  const int d0 = blockIdx.y * 64;
  const int bk = blockIdx.z;
  const int b = bk / HKV, kvh = bk % HKV;
#pragma unroll
  for (int i = 0; i < 4; ++i) {
    int key = i * 16 + (threadIdx.x >> 4);
    int d4 = (threadIdx.x & 15) * 4;
    *reinterpret_cast<ushort2*>(&tile[key][d4]) = *reinterpret_cast<const ushort2*>(
        &v[(size_t)(b * L_ + k0 + key) * rowStride + colOff + kvh * DH + d0 + d4]);
    *reinterpret_cast<ushort2*>(&tile[key][d4 + 2]) = *reinterpret_cast<const ushort2*>(
        &v[(size_t)(b * L_ + k0 + key) * rowStride + colOff + kvh * DH + d0 + d4 + 2]);
  }
  __syncthreads();
  const int d = threadIdx.x >> 2;
  const int kq = (threadIdx.x & 3) * 16;
  u16* orow = Vt + ((size_t)(bk * DH + d0 + d)) * L_ + k0 + kq;
#pragma unroll
  for (int j = 0; j < 16; ++j) orow[j] = tile[kq + j][d];
}

// ---------------------------------------------------------------------------
// bf16 MFMA GEMM: R10's m97 structure (single-buffer, 2x __syncthreads,
// 128x128, BK=32) + slot-major LDS (conflict-free fragment reads, proven
// R11/R12) + bijective XCD swizzle (1D grid, nwg % 8 == 0).
// ---------------------------------------------------------------------------
#define GBM 128
#define GBN 128
#define GBK 32

template <bool BF16OUT>
__global__ __launch_bounds__(256) void gemm_bf16_kernel(
    const u16* __restrict__ A, const u16* __restrict__ W,
    const float* __restrict__ bias, void* __restrict__ Cv,
    int M, int N, int K)
{
  // slot-major chunks: chunk = slot*128 + row, each 16 B (8 bf16), slot = k/8
  __shared__ u16 As[GBM * GBK];   // 512 chunks, 8 KB
  __shared__ u16 Bs[GBN * GBK];   // 512 chunks, 8 KB

  const int tid = threadIdx.x;
  const int wave = tid >> 6;
  const int lane = tid & 63;
  const int lr = lane & 15;
  const int lg = lane >> 4;

  // bijective XCD-chunked swizzle (nwg % 8 == 0)
  const int nwg = gridDim.x;
  const int qch = nwg >> 3;
  const int bid = blockIdx.x;
  const int wgid = (bid & 7) * qch + (bid >> 3);
  const int nx = N / GBN;
  const int bm = (wgid / nx) * GBM;
  const int bn = (wgid % nx) * GBN;

  const int wm = (wave >> 1) * 64;
  const int wn = (wave & 1) * 64;

  f32x4 acc[4][4];
#pragma unroll
  for (int i = 0; i < 4; ++i)
#pragma unroll
    for (int j = 0; j < 4; ++j) acc[i][j] = (f32x4){0.f, 0.f, 0.f, 0.f};

  // staging: 512 chunks/matrix; thread covers chunks c0 and c1
  const int c0 = wave * 64 + lane;          // 0..255 (slots 0..1)
  const int c1 = 256 + c0;                  // 256..511 (slots 2..3)
  const u16* gA0 = A + (size_t)(bm + (c0 & 127)) * K + (c0 >> 7) * 8;
  const u16* gA1 = A + (size_t)(bm + (c1 & 127)) * K + (c1 >> 7) * 8;
  const u16* gB0 = W + (size_t)(bn + (c0 & 127)) * K + (c0 >> 7) * 8;
  const u16* gB1 = W + (size_t)(bn + (c1 & 127)) * K + (c1 >> 7) * 8;
  u16* lA0 = &As[(wave * 64) * 8];
  u16* lA1 = &As[(256 + wave * 64) * 8];
  u16* lB0 = &Bs[(wave * 64) * 8];
  u16* lB1 = &Bs[(256 + wave * 64) * 8];

  for (int k0 = 0; k0 < K; k0 += GBK) {
    __syncthreads();   // previous compute done before overwrite
    __builtin_amdgcn_global_load_lds(GLB(gA0 + k0), LDS(lA0), 16, 0, 0);
    __builtin_amdgcn_global_load_lds(GLB(gA1 + k0), LDS(lA1), 16, 0, 0);
    __builtin_amdgcn_global_load_lds(GLB(gB0 + k0), LDS(lB0), 16, 0, 0);
    __builtin_amdgcn_global_load_lds(GLB(gB1 + k0), LDS(lB1), 16, 0, 0);
    __syncthreads();   // loads landed

    short8 af[4], bf[4];
#pragma unroll
    for (int mi = 0; mi < 4; ++mi)
      af[mi] = *reinterpret_cast<const short8*>(&As[(lg * 128 + wm + mi * 16 + lr) * 8]);
#pragma unroll
    for (int ni = 0; ni < 4; ++ni)
      bf[ni] = *reinterpret_cast<const short8*>(&Bs[(lg * 128 + wn + ni * 16 + lr) * 8]);
#pragma unroll
    for (int mi = 0; mi < 4; ++mi)
#pragma unroll
      for (int ni = 0; ni < 4; ++ni)
        acc[mi][ni] = __builtin_amdgcn_mfma_f32_16x16x32_bf16(af[mi], bf[ni], acc[mi][ni], 0, 0, 0);
  }

#pragma unroll
  for (int ni = 0; ni < 4; ++ni) {
    int col = bn + wn + ni * 16 + lr;
    float bv = (bias != nullptr) ? bias[col] : 0.f;
#pragma unroll
    for (int mi = 0; mi < 4; ++mi) {
#pragma unroll
      for (int r = 0; r < 4; ++r) {
        int row = bm + wm + mi * 16 + lg * 4 + r;
        float val = acc[mi][ni][r] + bv;
        if constexpr (BF16OUT)
          ((u16*)Cv)[(size_t)row * N + col] = f2bf(val);
        else
          ((float*)Cv)[(size_t)row * N + col] = val;
      }
    }
  }
}

// ---------------------------------------------------------------------------
// Flash attention, LDS K/V shared by 4 heads, counted-vmcnt pipeline (T3/T4).
// Block = 4 waves (256 thr) = 4 heads x ONE 32-row q-tile. Grid 512 = 2
// blocks/CU; blocks i and i+256 carry tiles 63-u and u (65 steps per CU).
// ---------------------------------------------------------------------------
__device__ __forceinline__ void head_step(
    const short8 qB[8], const short8 kc[8], const short8 vv[8],
    int j0, int q0, int l5, int hi, float* cbufw,
    f32x16 O[4], float& mrun, float& lrun)
{
  f32x16 accl, acch;
#pragma unroll
  for (int r = 0; r < 16; ++r) { accl[r] = 0.f; acch[r] = 0.f; }
#pragma unroll
  for (int s = 0; s < 4; ++s)
    accl = __builtin_amdgcn_mfma_f32_32x32x16_bf16(kc[s], qB[s], accl, 0, 0, 0);
#pragma unroll
  for (int s = 4; s < 8; ++s)
    acch = __builtin_amdgcn_mfma_f32_32x32x16_bf16(kc[s], qB[s], acch, 0, 0, 0);

  float S[16];
#pragma unroll
  for (int r = 0; r < 16; ++r) S[r] = accl[r] + acch[r];

  if (j0 == q0) {
#pragma unroll
    for (int r = 0; r < 16; ++r) {
      int crow = (r & 3) + 8 * (r >> 2) + 4 * hi;
      if (crow > l5) S[r] = -INFINITY;
    }
  }

  float t8[8], t4[4], t2[2];
#pragma unroll
  for (int r = 0; r < 8; ++r) t8[r] = fmaxf(S[2 * r], S[2 * r + 1]);
#pragma unroll
  for (int r = 0; r < 4; ++r) t4[r] = fmaxf(t8[2 * r], t8[2 * r + 1]);
  t2[0] = fmaxf(t4[0], t4[1]); t2[1] = fmaxf(t4[2], t4[3]);
  float pmax = fmaxf(t2[0], t2[1]);
  pmax = fmaxf(pmax, __shfl_xor(pmax, 32));

  if (__any(pmax > mrun + 8.0f)) {
    float mnew = fmaxf(mrun, pmax);
    float corr = __expf(mrun - mnew);
    mrun = mnew;
    lrun *= corr;
    if (hi == 0) cbufw[l5] = corr;
    float4 cr[4];
#pragma unroll
    for (int g = 0; g < 4; ++g)
      cr[g] = *reinterpret_cast<const float4*>(&cbufw[8 * g + 4 * hi]);
#pragma unroll
    for (int n = 0; n < 4; ++n)
#pragma unroll
      for (int r = 0; r < 16; ++r)
        O[n][r] *= (&cr[r >> 2].x)[r & 3];
  }

  float p[16];
#pragma unroll
  for (int r = 0; r < 16; ++r) p[r] = __expf(S[r] - mrun);
#pragma unroll
  for (int r = 0; r < 8; ++r) t8[r] = p[2 * r] + p[2 * r + 1];
#pragma unroll
  for (int r = 0; r < 4; ++r) t4[r] = t8[2 * r] + t8[2 * r + 1];
  t2[0] = t4[0] + t4[1]; t2[1] = t4[2] + t4[3];
  lrun += t2[0] + t2[1];

  u32 w[8];
#pragma unroll
  for (int t = 0; t < 8; ++t) w[t] = cvt_pk_bf16(p[2 * t], p[2 * t + 1]);
  permswap(w[0], w[2]); permswap(w[1], w[3]);
  permswap(w[4], w[6]); permswap(w[5], w[7]);
  short8 pa0 = __builtin_bit_cast(short8, (u32x4){w[0], w[1], w[2], w[3]});
  short8 pa1 = __builtin_bit_cast(short8, (u32x4){w[4], w[5], w[6], w[7]});

#pragma unroll
  for (int n = 0; n < 4; ++n) {
    O[n] = __builtin_amdgcn_mfma_f32_32x32x16_bf16(pa0, vv[n * 2 + 0], O[n], 0, 0, 0);
    O[n] = __builtin_amdgcn_mfma_f32_32x32x16_bf16(pa1, vv[n * 2 + 1], O[n], 0, 0, 0);
  }
}

__device__ __forceinline__ void head_epilogue(
    const f32x16 O[4], float lrun, int l5, int hi, float* cbufw,
    u16* __restrict__ obase)
{
  float ltot = lrun + __shfl_xor(lrun, 32);
  if (hi == 0) cbufw[l5] = ltot;
  float4 lv[4];
#pragma unroll
  for (int gg = 0; gg < 4; ++gg)
    lv[gg] = *reinterpret_cast<const float4*>(&cbufw[8 * gg + 4 * hi]);
#pragma unroll
  for (int r = 0; r < 16; ++r) {
    int crow = (r & 3) + 8 * (r >> 2) + 4 * hi;
    float inv = __builtin_amdgcn_rcpf((&lv[r >> 2].x)[r & 3]);
    u16* orow = obase + (size_t)crow * (HQ * DH) + l5;
#pragma unroll
    for (int n = 0; n < 4; ++n)
      orow[n * 32] = f2bf(O[n][r] * inv);
  }
}

__global__ __launch_bounds__(256, 2) void flash_attn_pipe_kernel(
    const u16* __restrict__ Qb, const u16* __restrict__ Kb,
    const u16* __restrict__ Vt, u16* __restrict__ ab)
{
  const int tid = threadIdx.x;
  const int wave = tid >> 6;
  const int lane = tid & 63;
  const int l5 = lane & 31;
  const int hi = lane >> 5;

  const int bid = blockIdx.x;
  const int half = bid >> 8;
  const int u = (bid >> 3) & 31;
  const int x = bid & 7;
  const int c = x >> 1;
  const int hh = x & 1;
  const int b = c >> 1, kvh = c & 1;
  const int h = kvh * 8 + hh * 4 + wave;
  const int t = half ? u : (63 - u);
  const int q0 = 32 * t;
  const int nst = t + 1;
  const int bk = b * HKV + kvh;

  __shared__ u16 Ks[2][32 * 128];
  __shared__ u16 Vs[2][128 * 32];
  __shared__ __align__(16) float cbuf[4][32];
  float* cbufw = cbuf[wave];

  const u16* Kg = Kb + (size_t)(b * L_) * (HKV * DH) + kvh * DH;
  const u16* Vg = Vt + (size_t)(bk * DH) * L_;

  auto stage = [&](int s) {
    const int buf = s & 1;
    const int j0 = s * 32;
#pragma unroll
    for (int q = 0; q < 2; ++q) {
      int cnk = (q * 4 + wave) * 64 + lane;
      int key = cnk >> 4, slot = cnk & 15;
      const u16* src = Kg + (size_t)(j0 + key) * (HKV * DH) + (slot ^ (key & 7)) * 8;
      __builtin_amdgcn_global_load_lds(GLB(src), LDS(&Ks[buf][(q * 4 + wave) * 64 * 8]), 16, 0, 0);
    }
#pragma unroll
    for (int q = 0; q < 2; ++q) {
      int cnk = (q * 4 + wave) * 64 + lane;
      int d = cnk >> 2, slot = cnk & 3;
      const u16* src = Vg + (size_t)d * L_ + j0 + (slot ^ ((d >> 1) & 3)) * 8;
      __builtin_amdgcn_global_load_lds(GLB(src), LDS(&Vs[buf][(q * 4 + wave) * 64 * 8]), 16, 0, 0);
    }
  };

  const u16* qrow = Qb + ((size_t)(b * L_ + q0 + l5)) * (HQ * DH) + h * DH + hi * 8;
  short8 qB[8];
#pragma unroll
  for (int ss = 0; ss < 8; ++ss)
    qB[ss] = *reinterpret_cast<const short8*>(qrow + ss * 16);

  f32x16 O[4];
#pragma unroll
  for (int n = 0; n < 4; ++n)
#pragma unroll
    for (int r = 0; r < 16; ++r) O[n][r] = 0.f;
  float mrun = -INFINITY, lrun = 0.f;

  stage(0);
  if (nst > 1) stage(1);

#pragma unroll 1
  for (int s = 0; s < nst; ++s) {
    if (s + 1 < nst) { asm volatile("s_waitcnt vmcnt(4)" ::: "memory"); }
    else             { asm volatile("s_waitcnt vmcnt(0)" ::: "memory"); }
    __builtin_amdgcn_s_barrier();
    __builtin_amdgcn_sched_barrier(0);

    const int cur = s & 1;
    short8 kc[8], vv[8];
#pragma unroll
    for (int ss = 0; ss < 8; ++ss) {
      int slot = (2 * ss + hi) ^ (l5 & 7);
      kc[ss] = *reinterpret_cast<const short8*>(&Ks[cur][l5 * 128 + slot * 8]);
    }
#pragma unroll
    for (int n = 0; n < 4; ++n) {
#pragma unroll
      for (int cc = 0; cc < 2; ++cc) {
        int d = n * 32 + l5;
        int slot = (cc * 2 + hi) ^ ((d >> 1) & 3);
        vv[n * 2 + cc] = *reinterpret_cast<const short8*>(&Vs[cur][d * 32 + slot * 8]);
      }
    }
    asm volatile("s_waitcnt lgkmcnt(0)" ::: "memory");
    __builtin_amdgcn_sched_barrier(0);
    __builtin_amdgcn_s_barrier();
    if (s + 2 < nst) stage(s + 2);

    head_step(qB, kc, vv, s * 32, q0, l5, hi, cbufw, O, mrun, lrun);
  }

  u16* obase = ab + (size_t)(b * L_ + q0) * (HQ * DH) + h * DH;
  head_epilogue(O, lrun, l5, hi, cbufw, obase);
}

// ---------------------------------------------------------------------------
// launch
// ---------------------------------------------------------------------------
extern "C" void kernel_launch(void* const* d_in, const int* in_sizes, int n_in,
                              void* d_out, int out_size, void* d_ws, size_t ws_size,
                              hipStream_t stream) {
  const float* x  = (const float*)d_in[0];
  const float* wq = (const float*)d_in[1];
  const float* wk = (const float*)d_in[2];
  const float* wv = (const float*)d_in[3];
  const float* wo = (const float*)d_in[4];
  const float* bq = (const float*)d_in[5];
  const float* bk = (const float*)d_in[6];
  const float* bv = (const float*)d_in[7];
  float* out = (float*)d_out;

  const int M = B_ * L_;
  const int NQKV = HQ * DH + 2 * HKV * DH;  // 2560
  const size_t QN = (size_t)B_ * L_ * HQ * DH;
  const size_t KN = (size_t)B_ * L_ * HKV * DH;
  const size_t TN = (size_t)L_ * (DH / 2);

  float* ws = (float*)d_ws;
  float* ct   = ws;
  float* st   = ct + TN;
  float* bqkv = st + TN;
  u16* qkvb   = (u16*)(bqkv + 2560);        // bf16 QKV projection output
  u16* xb     = qkvb + (size_t)M * NQKV;
  u16* wqkvb  = xb + (size_t)M * E_;
  u16* Qbf    = wqkvb + (size_t)NQKV * E_;
  u16* Kbf    = Qbf + QN;
  u16* Vt     = Kbf + KN;
  u16* ab     = qkvb;   // alias: qkvb dead after rope/transpose
  u16* wob    = Qbf;    // alias: Qbf dead after attention

  const float scale = 0.08838834764831845f;

  rope_tab_kernel<<<(L_ * (DH / 2) + 255) / 256, 256, 0, stream>>>(ct, st);

  cvt_bf16_kernel<<<(int)(QN / 8 / 256), 256, 0, stream>>>(x, xb, (int)QN);
  cvt_bf16_kernel<<<(HQ * DH * E_) / 8 / 256, 256, 0, stream>>>(wq, wqkvb, HQ * DH * E_);
  cvt_bf16_kernel<<<(HKV * DH * E_) / 8 / 256, 256, 0, stream>>>(
      wk, wqkvb + (size_t)(HQ * DH) * E_, HKV * DH * E_);
  cvt_bf16_kernel<<<(HKV * DH * E_) / 8 / 256, 256, 0, stream>>>(
      wv, wqkvb + (size_t)(HQ * DH + HKV * DH) * E_, HKV * DH * E_);

  hipMemcpyAsync(bqkv, bq, (size_t)HQ * DH * 4, hipMemcpyDeviceToDevice, stream);
  hipMemcpyAsync(bqkv + HQ * DH, bk, (size_t)HKV * DH * 4, hipMemcpyDeviceToDevice, stream);
  hipMemcpyAsync(bqkv + HQ * DH + HKV * DH, bv, (size_t)HKV * DH * 4, hipMemcpyDeviceToDevice, stream);

  // fused QKV projection: grid 20*32 = 640 blocks (1D, XCD-swizzled)
  gemm_bf16_kernel<true><<<dim3((NQKV / GBN) * (M / GBM)), 256, 0, stream>>>(
      xb, wqkvb, bqkv, qkvb, M, NQKV, E_);

  {
    int totq = B_ * L_ * HQ * 64;
    rope_convert_kernel<<<(totq + 255) / 256, 256, 0, stream>>>(
        qkvb, Qbf, ct, st, HQ, NQKV, 0, scale, totq);
    int totk = B_ * L_ * HKV * 64;
    rope_convert_kernel<<<(totk + 255) / 256, 256, 0, stream>>>(
        qkvb, Kbf, ct, st, HKV, NQKV, HQ * DH, 1.0f, totk);
  }
  transpose_v_kernel<<<dim3(L_ / 64, DH / 64, B_ * HKV), 256, 0, stream>>>(
      qkvb, Vt, NQKV, HQ * DH + HKV * DH);

  flash_attn_pipe_kernel<<<dim3(512), 256, 0, stream>>>(Qbf, Kbf, Vt, ab);

  cvt_bf16_kernel<<<(E_ * E_) / 8 / 256, 256, 0, stream>>>(wo, wob, E_ * E_);
  // O-projection: grid 16*32 = 512 blocks (1D, XCD-swizzled)
  gemm_bf16_kernel<false><<<dim3((E_ / GBN) * (M / GBM)), 256, 0, stream>>>(
      ab, wob, nullptr, out, M, E_, E_);
}

// Round 14
// 233.465 us; speedup vs baseline: 1.5123x; 1.2310x over previous
//
#include <hip/hip_runtime.h>
#include <math.h>

#define B_ 2
#define L_ 2048
#define E_ 2048
#define HQ 16
#define HKV 2
#define DH 128

typedef unsigned short u16;
typedef unsigned int u32;
typedef __attribute__((ext_vector_type(8))) short short8;
typedef __attribute__((ext_vector_type(4))) float f32x4;
typedef __attribute__((ext_vector_type(16))) float f32x16;
typedef __attribute__((ext_vector_type(4))) u32 u32x4;

static __device__ __forceinline__ u16 f2bf(float f) {
  unsigned int u = __float_as_uint(f);
  unsigned int r = (u + 0x7fffu + ((u >> 16) & 1u)) >> 16;
  return (u16)r;
}
static __device__ __forceinline__ float bf2f(u16 v) {
  return __uint_as_float(((u32)v) << 16);
}

static __device__ __forceinline__ u32 cvt_pk_bf16(float lo, float hi) {
  u32 r;
  asm volatile("v_cvt_pk_bf16_f32 %0, %1, %2" : "=v"(r) : "v"(lo), "v"(hi));
  return r;
}
// swaps a's upper-half lanes with b's lower-half lanes (gfx950).
static __device__ __forceinline__ void permswap(u32& a, u32& b) {
  asm volatile("v_permlane32_swap_b32 %0, %1" : "+v"(a), "+v"(b));
}

#define GLB(p) ((const __attribute__((address_space(1))) void*)(p))
#define LDS(p) ((__attribute__((address_space(3))) void*)(p))

// ---------------------------------------------------------------------------
// fp32 -> bf16 convert
// ---------------------------------------------------------------------------
__global__ void cvt_bf16_kernel(const float* __restrict__ in,
                                u16* __restrict__ out, int n) {
  int i = (blockIdx.x * 256 + threadIdx.x) * 8;
  if (i >= n) return;
  float4 a = *reinterpret_cast<const float4*>(in + i);
  float4 b = *reinterpret_cast<const float4*>(in + i + 4);
  short8 r;
  r[0] = (short)f2bf(a.x); r[1] = (short)f2bf(a.y);
  r[2] = (short)f2bf(a.z); r[3] = (short)f2bf(a.w);
  r[4] = (short)f2bf(b.x); r[5] = (short)f2bf(b.y);
  r[6] = (short)f2bf(b.z); r[7] = (short)f2bf(b.w);
  *reinterpret_cast<short8*>(out + i) = r;
}

// ---------------------------------------------------------------------------
// RoPE table
// ---------------------------------------------------------------------------
__global__ void rope_tab_kernel(float* __restrict__ ctab, float* __restrict__ stab) {
  int idx = blockIdx.x * 256 + threadIdx.x;
  if (idx >= L_ * (DH / 2)) return;
  int pos = idx >> 6;
  int f = idx & 63;
  float inv_freq = powf(10000.0f, -(float)f * (1.0f / 64.0f));
  float ang = (float)pos * inv_freq;
  float s, c;
  sincosf(ang, &s, &c);
  ctab[idx] = c;
  stab[idx] = s;
}

// ---------------------------------------------------------------------------
// RoPE apply from bf16 fused-qkv buffer -> bf16 head-major buffer
// ---------------------------------------------------------------------------
__global__ void rope_convert_kernel(const u16* __restrict__ in,
                                    u16* __restrict__ outb,
                                    const float* __restrict__ ctab,
                                    const float* __restrict__ stab,
                                    int H, int rowStride, int colOff,
                                    float scale, int total) {
  int idx = blockIdx.x * 256 + threadIdx.x;
  if (idx >= total) return;
  int f = idx & 63;
  int row = idx >> 6;
  int h = row % H;
  int bl = row / H;
  int l = bl & (L_ - 1);
  size_t sbase = (size_t)bl * rowStride + colOff + (size_t)h * DH;
  size_t dbase = (size_t)bl * ((size_t)H * DH) + (size_t)h * DH;
  float x1 = bf2f(in[sbase + f]);
  float x2 = bf2f(in[sbase + 64 + f]);
  float c = ctab[l * 64 + f];
  float s = stab[l * 64 + f];
  outb[dbase + f]      = f2bf((x1 * c - x2 * s) * scale);
  outb[dbase + 64 + f] = f2bf((x2 * c + x1 * s) * scale);
}

// ---------------------------------------------------------------------------
// V transpose from bf16 qkv buffer: -> Vt[(b*HKV+kvh)*128+d][key]
// ---------------------------------------------------------------------------
__global__ __launch_bounds__(256) void transpose_v_kernel(
    const u16* __restrict__ v, u16* __restrict__ Vt,
    int rowStride, int colOff) {
  __shared__ u16 tile[64][68];
  const int k0 = blockIdx.x * 64;
  const int d0 = blockIdx.y * 64;
  const int bk = blockIdx.z;
  const int b = bk / HKV, kvh = bk % HKV;
#pragma unroll
  for (int i = 0; i < 4; ++i) {
    int key = i * 16 + (threadIdx.x >> 4);
    int d4 = (threadIdx.x & 15) * 4;
    *reinterpret_cast<ushort2*>(&tile[key][d4]) = *reinterpret_cast<const ushort2*>(
        &v[(size_t)(b * L_ + k0 + key) * rowStride + colOff + kvh * DH + d0 + d4]);
    *reinterpret_cast<ushort2*>(&tile[key][d4 + 2]) = *reinterpret_cast<const ushort2*>(
        &v[(size_t)(b * L_ + k0 + key) * rowStride + colOff + kvh * DH + d0 + d4 + 2]);
  }
  __syncthreads();
  const int d = threadIdx.x >> 2;
  const int kq = (threadIdx.x & 3) * 16;
  u16* orow = Vt + ((size_t)(bk * DH + d0 + d)) * L_ + k0 + kq;
#pragma unroll
  for (int j = 0; j < 16; ++j) orow[j] = tile[kq + j][d];
}

// ---------------------------------------------------------------------------
// bf16 MFMA GEMM: R10's m97 structure exactly (single-buffer, 2x
// __syncthreads, 128x128, BK=32, 2D grid), with ONE change: XOR-slot LDS
// mapping. chunk = row*4 + (slot ^ ((row>>1)&3)); source stays 64B/row
// contiguous (coalescing = R10), fragment reads hit each bank-slot 2x
// (2-way = free, vs R10's 8-way conflict).
// ---------------------------------------------------------------------------
#define GBM 128
#define GBN 128
#define GBK 32

template <bool BF16OUT>
__global__ __launch_bounds__(256) void gemm_bf16_kernel(
    const u16* __restrict__ A, const u16* __restrict__ W,
    const float* __restrict__ bias, void* __restrict__ Cv,
    int M, int N, int K)
{
  // chunk c (16 B) at LDS offset c*16 holds A[bm + (c>>2)][k0 + sl*8 ..]
  // where sl = (c&3) ^ (((c>>2)>>1)&3)
  __shared__ u16 As[GBM * GBK];   // 512 chunks, 8 KB
  __shared__ u16 Bs[GBN * GBK];   // 512 chunks, 8 KB

  const int tid = threadIdx.x;
  const int wave = tid >> 6;
  const int lane = tid & 63;
  const int lr = lane & 15;
  const int lg = lane >> 4;
  const int bm = blockIdx.y * GBM;
  const int bn = blockIdx.x * GBN;
  const int wm = (wave >> 1) * 64;
  const int wn = (wave & 1) * 64;

  f32x4 acc[4][4];
#pragma unroll
  for (int i = 0; i < 4; ++i)
#pragma unroll
    for (int j = 0; j < 4; ++j) acc[i][j] = (f32x4){0.f, 0.f, 0.f, 0.f};

  // staging: lane covers chunks c0 = wave*64+lane and c1 = 256+c0.
  // row(c0) = wave*16 + (lane>>2); source slot = (lane&3) ^ ((lane>>3)&3)
  // (same 64B line per 4-lane group -> coalescing identical to R10)
  const int r0 = wave * 16 + (lane >> 2);
  const int sl = (lane & 3) ^ ((lane >> 3) & 3);
  const u16* gA0 = A + (size_t)(bm + r0) * K + sl * 8;
  const u16* gA1 = A + (size_t)(bm + 64 + r0) * K + sl * 8;
  const u16* gB0 = W + (size_t)(bn + r0) * K + sl * 8;
  const u16* gB1 = W + (size_t)(bn + 64 + r0) * K + sl * 8;
  u16* lA0 = &As[(wave * 64) * 8];
  u16* lA1 = &As[(256 + wave * 64) * 8];
  u16* lB0 = &Bs[(wave * 64) * 8];
  u16* lB1 = &Bs[(256 + wave * 64) * 8];

  // fragment chunk XOR term: constant per thread (row low bits = lr)
  const int fxor = ((lr >> 1) & 3);

  for (int k0 = 0; k0 < K; k0 += GBK) {
    __syncthreads();   // previous compute done before overwrite
    __builtin_amdgcn_global_load_lds(GLB(gA0 + k0), LDS(lA0), 16, 0, 0);
    __builtin_amdgcn_global_load_lds(GLB(gA1 + k0), LDS(lA1), 16, 0, 0);
    __builtin_amdgcn_global_load_lds(GLB(gB0 + k0), LDS(lB0), 16, 0, 0);
    __builtin_amdgcn_global_load_lds(GLB(gB1 + k0), LDS(lB1), 16, 0, 0);
    __syncthreads();   // loads landed

    short8 af[4], bf[4];
#pragma unroll
    for (int mi = 0; mi < 4; ++mi) {
      int row = wm + mi * 16 + lr;
      af[mi] = *reinterpret_cast<const short8*>(&As[(row * 4 + (lg ^ fxor)) * 8]);
    }
#pragma unroll
    for (int ni = 0; ni < 4; ++ni) {
      int row = wn + ni * 16 + lr;
      bf[ni] = *reinterpret_cast<const short8*>(&Bs[(row * 4 + (lg ^ fxor)) * 8]);
    }
#pragma unroll
    for (int mi = 0; mi < 4; ++mi)
#pragma unroll
      for (int ni = 0; ni < 4; ++ni)
        acc[mi][ni] = __builtin_amdgcn_mfma_f32_16x16x32_bf16(af[mi], bf[ni], acc[mi][ni], 0, 0, 0);
  }

#pragma unroll
  for (int ni = 0; ni < 4; ++ni) {
    int col = bn + wn + ni * 16 + lr;
    float bv = (bias != nullptr) ? bias[col] : 0.f;
#pragma unroll
    for (int mi = 0; mi < 4; ++mi) {
#pragma unroll
      for (int r = 0; r < 4; ++r) {
        int row = bm + wm + mi * 16 + lg * 4 + r;
        float val = acc[mi][ni][r] + bv;
        if constexpr (BF16OUT)
          ((u16*)Cv)[(size_t)row * N + col] = f2bf(val);
        else
          ((float*)Cv)[(size_t)row * N + col] = val;
      }
    }
  }
}

// ---------------------------------------------------------------------------
// Flash attention, LDS K/V shared by 4 heads, counted-vmcnt pipeline (T3/T4).
// Block = 4 waves (256 thr) = 4 heads x ONE 32-row q-tile. Grid 512 = 2
// blocks/CU; blocks i and i+256 carry tiles 63-u and u (65 steps per CU).
// ---------------------------------------------------------------------------
__device__ __forceinline__ void head_step(
    const short8 qB[8], const short8 kc[8], const short8 vv[8],
    int j0, int q0, int l5, int hi, float* cbufw,
    f32x16 O[4], float& mrun, float& lrun)
{
  f32x16 accl, acch;
#pragma unroll
  for (int r = 0; r < 16; ++r) { accl[r] = 0.f; acch[r] = 0.f; }
#pragma unroll
  for (int s = 0; s < 4; ++s)
    accl = __builtin_amdgcn_mfma_f32_32x32x16_bf16(kc[s], qB[s], accl, 0, 0, 0);
#pragma unroll
  for (int s = 4; s < 8; ++s)
    acch = __builtin_amdgcn_mfma_f32_32x32x16_bf16(kc[s], qB[s], acch, 0, 0, 0);

  float S[16];
#pragma unroll
  for (int r = 0; r < 16; ++r) S[r] = accl[r] + acch[r];

  if (j0 == q0) {
#pragma unroll
    for (int r = 0; r < 16; ++r) {
      int crow = (r & 3) + 8 * (r >> 2) + 4 * hi;
      if (crow > l5) S[r] = -INFINITY;
    }
  }

  float t8[8], t4[4], t2[2];
#pragma unroll
  for (int r = 0; r < 8; ++r) t8[r] = fmaxf(S[2 * r], S[2 * r + 1]);
#pragma unroll
  for (int r = 0; r < 4; ++r) t4[r] = fmaxf(t8[2 * r], t8[2 * r + 1]);
  t2[0] = fmaxf(t4[0], t4[1]); t2[1] = fmaxf(t4[2], t4[3]);
  float pmax = fmaxf(t2[0], t2[1]);
  pmax = fmaxf(pmax, __shfl_xor(pmax, 32));

  if (__any(pmax > mrun + 8.0f)) {
    float mnew = fmaxf(mrun, pmax);
    float corr = __expf(mrun - mnew);
    mrun = mnew;
    lrun *= corr;
    if (hi == 0) cbufw[l5] = corr;
    float4 cr[4];
#pragma unroll
    for (int g = 0; g < 4; ++g)
      cr[g] = *reinterpret_cast<const float4*>(&cbufw[8 * g + 4 * hi]);
#pragma unroll
    for (int n = 0; n < 4; ++n)
#pragma unroll
      for (int r = 0; r < 16; ++r)
        O[n][r] *= (&cr[r >> 2].x)[r & 3];
  }

  float p[16];
#pragma unroll
  for (int r = 0; r < 16; ++r) p[r] = __expf(S[r] - mrun);
#pragma unroll
  for (int r = 0; r < 8; ++r) t8[r] = p[2 * r] + p[2 * r + 1];
#pragma unroll
  for (int r = 0; r < 4; ++r) t4[r] = t8[2 * r] + t8[2 * r + 1];
  t2[0] = t4[0] + t4[1]; t2[1] = t4[2] + t4[3];
  lrun += t2[0] + t2[1];

  u32 w[8];
#pragma unroll
  for (int t = 0; t < 8; ++t) w[t] = cvt_pk_bf16(p[2 * t], p[2 * t + 1]);
  permswap(w[0], w[2]); permswap(w[1], w[3]);
  permswap(w[4], w[6]); permswap(w[5], w[7]);
  short8 pa0 = __builtin_bit_cast(short8, (u32x4){w[0], w[1], w[2], w[3]});
  short8 pa1 = __builtin_bit_cast(short8, (u32x4){w[4], w[5], w[6], w[7]});

#pragma unroll
  for (int n = 0; n < 4; ++n) {
    O[n] = __builtin_amdgcn_mfma_f32_32x32x16_bf16(pa0, vv[n * 2 + 0], O[n], 0, 0, 0);
    O[n] = __builtin_amdgcn_mfma_f32_32x32x16_bf16(pa1, vv[n * 2 + 1], O[n], 0, 0, 0);
  }
}

__device__ __forceinline__ void head_epilogue(
    const f32x16 O[4], float lrun, int l5, int hi, float* cbufw,
    u16* __restrict__ obase)
{
  float ltot = lrun + __shfl_xor(lrun, 32);
  if (hi == 0) cbufw[l5] = ltot;
  float4 lv[4];
#pragma unroll
  for (int gg = 0; gg < 4; ++gg)
    lv[gg] = *reinterpret_cast<const float4*>(&cbufw[8 * gg + 4 * hi]);
#pragma unroll
  for (int r = 0; r < 16; ++r) {
    int crow = (r & 3) + 8 * (r >> 2) + 4 * hi;
    float inv = __builtin_amdgcn_rcpf((&lv[r >> 2].x)[r & 3]);
    u16* orow = obase + (size_t)crow * (HQ * DH) + l5;
#pragma unroll
    for (int n = 0; n < 4; ++n)
      orow[n * 32] = f2bf(O[n][r] * inv);
  }
}

__global__ __launch_bounds__(256, 2) void flash_attn_pipe_kernel(
    const u16* __restrict__ Qb, const u16* __restrict__ Kb,
    const u16* __restrict__ Vt, u16* __restrict__ ab)
{
  const int tid = threadIdx.x;
  const int wave = tid >> 6;
  const int lane = tid & 63;
  const int l5 = lane & 31;
  const int hi = lane >> 5;

  const int bid = blockIdx.x;
  const int half = bid >> 8;
  const int u = (bid >> 3) & 31;
  const int x = bid & 7;
  const int c = x >> 1;
  const int hh = x & 1;
  const int b = c >> 1, kvh = c & 1;
  const int h = kvh * 8 + hh * 4 + wave;
  const int t = half ? u : (63 - u);
  const int q0 = 32 * t;
  const int nst = t + 1;
  const int bk = b * HKV + kvh;

  __shared__ u16 Ks[2][32 * 128];
  __shared__ u16 Vs[2][128 * 32];
  __shared__ __align__(16) float cbuf[4][32];
  float* cbufw = cbuf[wave];

  const u16* Kg = Kb + (size_t)(b * L_) * (HKV * DH) + kvh * DH;
  const u16* Vg = Vt + (size_t)(bk * DH) * L_;

  auto stage = [&](int s) {
    const int buf = s & 1;
    const int j0 = s * 32;
#pragma unroll
    for (int q = 0; q < 2; ++q) {
      int cnk = (q * 4 + wave) * 64 + lane;
      int key = cnk >> 4, slot = cnk & 15;
      const u16* src = Kg + (size_t)(j0 + key) * (HKV * DH) + (slot ^ (key & 7)) * 8;
      __builtin_amdgcn_global_load_lds(GLB(src), LDS(&Ks[buf][(q * 4 + wave) * 64 * 8]), 16, 0, 0);
    }
#pragma unroll
    for (int q = 0; q < 2; ++q) {
      int cnk = (q * 4 + wave) * 64 + lane;
      int d = cnk >> 2, slot = cnk & 3;
      const u16* src = Vg + (size_t)d * L_ + j0 + (slot ^ ((d >> 1) & 3)) * 8;
      __builtin_amdgcn_global_load_lds(GLB(src), LDS(&Vs[buf][(q * 4 + wave) * 64 * 8]), 16, 0, 0);
    }
  };

  const u16* qrow = Qb + ((size_t)(b * L_ + q0 + l5)) * (HQ * DH) + h * DH + hi * 8;
  short8 qB[8];
#pragma unroll
  for (int ss = 0; ss < 8; ++ss)
    qB[ss] = *reinterpret_cast<const short8*>(qrow + ss * 16);

  f32x16 O[4];
#pragma unroll
  for (int n = 0; n < 4; ++n)
#pragma unroll
    for (int r = 0; r < 16; ++r) O[n][r] = 0.f;
  float mrun = -INFINITY, lrun = 0.f;

  stage(0);
  if (nst > 1) stage(1);

#pragma unroll 1
  for (int s = 0; s < nst; ++s) {
    if (s + 1 < nst) { asm volatile("s_waitcnt vmcnt(4)" ::: "memory"); }
    else             { asm volatile("s_waitcnt vmcnt(0)" ::: "memory"); }
    __builtin_amdgcn_s_barrier();
    __builtin_amdgcn_sched_barrier(0);

    const int cur = s & 1;
    short8 kc[8], vv[8];
#pragma unroll
    for (int ss = 0; ss < 8; ++ss) {
      int slot = (2 * ss + hi) ^ (l5 & 7);
      kc[ss] = *reinterpret_cast<const short8*>(&Ks[cur][l5 * 128 + slot * 8]);
    }
#pragma unroll
    for (int n = 0; n < 4; ++n) {
#pragma unroll
      for (int cc = 0; cc < 2; ++cc) {
        int d = n * 32 + l5;
        int slot = (cc * 2 + hi) ^ ((d >> 1) & 3);
        vv[n * 2 + cc] = *reinterpret_cast<const short8*>(&Vs[cur][d * 32 + slot * 8]);
      }
    }
    asm volatile("s_waitcnt lgkmcnt(0)" ::: "memory");
    __builtin_amdgcn_sched_barrier(0);
    __builtin_amdgcn_s_barrier();
    if (s + 2 < nst) stage(s + 2);

    head_step(qB, kc, vv, s * 32, q0, l5, hi, cbufw, O, mrun, lrun);
  }

  u16* obase = ab + (size_t)(b * L_ + q0) * (HQ * DH) + h * DH;
  head_epilogue(O, lrun, l5, hi, cbufw, obase);
}

// ---------------------------------------------------------------------------
// launch
// ---------------------------------------------------------------------------
extern "C" void kernel_launch(void* const* d_in, const int* in_sizes, int n_in,
                              void* d_out, int out_size, void* d_ws, size_t ws_size,
                              hipStream_t stream) {
  const float* x  = (const float*)d_in[0];
  const float* wq = (const float*)d_in[1];
  const float* wk = (const float*)d_in[2];
  const float* wv = (const float*)d_in[3];
  const float* wo = (const float*)d_in[4];
  const float* bq = (const float*)d_in[5];
  const float* bk = (const float*)d_in[6];
  const float* bv = (const float*)d_in[7];
  float* out = (float*)d_out;

  const int M = B_ * L_;
  const int NQKV = HQ * DH + 2 * HKV * DH;  // 2560
  const size_t QN = (size_t)B_ * L_ * HQ * DH;
  const size_t KN = (size_t)B_ * L_ * HKV * DH;
  const size_t TN = (size_t)L_ * (DH / 2);

  float* ws = (float*)d_ws;
  float* ct   = ws;
  float* st   = ct + TN;
  float* bqkv = st + TN;
  u16* qkvb   = (u16*)(bqkv + 2560);        // bf16 QKV projection output
  u16* xb     = qkvb + (size_t)M * NQKV;
  u16* wqkvb  = xb + (size_t)M * E_;
  u16* Qbf    = wqkvb + (size_t)NQKV * E_;
  u16* Kbf    = Qbf + QN;
  u16* Vt     = Kbf + KN;
  u16* ab     = qkvb;   // alias: qkvb dead after rope/transpose
  u16* wob    = Qbf;    // alias: Qbf dead after attention

  const float scale = 0.08838834764831845f;

  rope_tab_kernel<<<(L_ * (DH / 2) + 255) / 256, 256, 0, stream>>>(ct, st);

  cvt_bf16_kernel<<<(int)(QN / 8 / 256), 256, 0, stream>>>(x, xb, (int)QN);
  cvt_bf16_kernel<<<(HQ * DH * E_) / 8 / 256, 256, 0, stream>>>(wq, wqkvb, HQ * DH * E_);
  cvt_bf16_kernel<<<(HKV * DH * E_) / 8 / 256, 256, 0, stream>>>(
      wk, wqkvb + (size_t)(HQ * DH) * E_, HKV * DH * E_);
  cvt_bf16_kernel<<<(HKV * DH * E_) / 8 / 256, 256, 0, stream>>>(
      wv, wqkvb + (size_t)(HQ * DH + HKV * DH) * E_, HKV * DH * E_);

  hipMemcpyAsync(bqkv, bq, (size_t)HQ * DH * 4, hipMemcpyDeviceToDevice, stream);
  hipMemcpyAsync(bqkv + HQ * DH, bk, (size_t)HKV * DH * 4, hipMemcpyDeviceToDevice, stream);
  hipMemcpyAsync(bqkv + HQ * DH + HKV * DH, bv, (size_t)HKV * DH * 4, hipMemcpyDeviceToDevice, stream);

  // fused QKV projection: [4096][2560]
  gemm_bf16_kernel<true><<<dim3(NQKV / GBN, M / GBM), 256, 0, stream>>>(
      xb, wqkvb, bqkv, qkvb, M, NQKV, E_);

  {
    int totq = B_ * L_ * HQ * 64;
    rope_convert_kernel<<<(totq + 255) / 256, 256, 0, stream>>>(
        qkvb, Qbf, ct, st, HQ, NQKV, 0, scale, totq);
    int totk = B_ * L_ * HKV * 64;
    rope_convert_kernel<<<(totk + 255) / 256, 256, 0, stream>>>(
        qkvb, Kbf, ct, st, HKV, NQKV, HQ * DH, 1.0f, totk);
  }
  transpose_v_kernel<<<dim3(L_ / 64, DH / 64, B_ * HKV), 256, 0, stream>>>(
      qkvb, Vt, NQKV, HQ * DH + HKV * DH);

  flash_attn_pipe_kernel<<<dim3(512), 256, 0, stream>>>(Qbf, Kbf, Vt, ab);

  cvt_bf16_kernel<<<(E_ * E_) / 8 / 256, 256, 0, stream>>>(wo, wob, E_ * E_);
  gemm_bf16_kernel<false><<<dim3(E_ / GBN, M / GBM), 256, 0, stream>>>(
      ab, wob, nullptr, out, M, E_, E_);
}

// Round 15
// 216.099 us; speedup vs baseline: 1.6338x; 1.0804x over previous
//
#include <hip/hip_runtime.h>
#include <math.h>

#define B_ 2
#define L_ 2048
#define E_ 2048
#define HQ 16
#define HKV 2
#define DH 128

typedef unsigned short u16;
typedef unsigned int u32;
typedef __attribute__((ext_vector_type(8))) short short8;
typedef __attribute__((ext_vector_type(4))) float f32x4;
typedef __attribute__((ext_vector_type(16))) float f32x16;
typedef __attribute__((ext_vector_type(4))) u32 u32x4;

static __device__ __forceinline__ u16 f2bf(float f) {
  unsigned int u = __float_as_uint(f);
  unsigned int r = (u + 0x7fffu + ((u >> 16) & 1u)) >> 16;
  return (u16)r;
}
static __device__ __forceinline__ float bf2f(u16 v) {
  return __uint_as_float(((u32)v) << 16);
}

static __device__ __forceinline__ u32 cvt_pk_bf16(float lo, float hi) {
  u32 r;
  asm volatile("v_cvt_pk_bf16_f32 %0, %1, %2" : "=v"(r) : "v"(lo), "v"(hi));
  return r;
}
// swaps a's upper-half lanes with b's lower-half lanes (gfx950).
static __device__ __forceinline__ void permswap(u32& a, u32& b) {
  asm volatile("v_permlane32_swap_b32 %0, %1" : "+v"(a), "+v"(b));
}

#define GLB(p) ((const __attribute__((address_space(1))) void*)(p))
#define LDS(p) ((__attribute__((address_space(3))) void*)(p))

// ---------------------------------------------------------------------------
// fp32 -> bf16 convert
// ---------------------------------------------------------------------------
__global__ void cvt_bf16_kernel(const float* __restrict__ in,
                                u16* __restrict__ out, int n) {
  int i = (blockIdx.x * 256 + threadIdx.x) * 8;
  if (i >= n) return;
  float4 a = *reinterpret_cast<const float4*>(in + i);
  float4 b = *reinterpret_cast<const float4*>(in + i + 4);
  short8 r;
  r[0] = (short)f2bf(a.x); r[1] = (short)f2bf(a.y);
  r[2] = (short)f2bf(a.z); r[3] = (short)f2bf(a.w);
  r[4] = (short)f2bf(b.x); r[5] = (short)f2bf(b.y);
  r[6] = (short)f2bf(b.z); r[7] = (short)f2bf(b.w);
  *reinterpret_cast<short8*>(out + i) = r;
}

// ---------------------------------------------------------------------------
// RoPE table
// ---------------------------------------------------------------------------
__global__ void rope_tab_kernel(float* __restrict__ ctab, float* __restrict__ stab) {
  int idx = blockIdx.x * 256 + threadIdx.x;
  if (idx >= L_ * (DH / 2)) return;
  int pos = idx >> 6;
  int f = idx & 63;
  float inv_freq = powf(10000.0f, -(float)f * (1.0f / 64.0f));
  float ang = (float)pos * inv_freq;
  float s, c;
  sincosf(ang, &s, &c);
  ctab[idx] = c;
  stab[idx] = s;
}

// ---------------------------------------------------------------------------
// RoPE apply from bf16 fused-qkv buffer -> bf16 head-major buffer
// ---------------------------------------------------------------------------
__global__ void rope_convert_kernel(const u16* __restrict__ in,
                                    u16* __restrict__ outb,
                                    const float* __restrict__ ctab,
                                    const float* __restrict__ stab,
                                    int H, int rowStride, int colOff,
                                    float scale, int total) {
  int idx = blockIdx.x * 256 + threadIdx.x;
  if (idx >= total) return;
  int f = idx & 63;
  int row = idx >> 6;
  int h = row % H;
  int bl = row / H;
  int l = bl & (L_ - 1);
  size_t sbase = (size_t)bl * rowStride + colOff + (size_t)h * DH;
  size_t dbase = (size_t)bl * ((size_t)H * DH) + (size_t)h * DH;
  float x1 = bf2f(in[sbase + f]);
  float x2 = bf2f(in[sbase + 64 + f]);
  float c = ctab[l * 64 + f];
  float s = stab[l * 64 + f];
  outb[dbase + f]      = f2bf((x1 * c - x2 * s) * scale);
  outb[dbase + 64 + f] = f2bf((x2 * c + x1 * s) * scale);
}

// ---------------------------------------------------------------------------
// V transpose from bf16 qkv buffer: -> Vt[(b*HKV+kvh)*128+d][key]
// ---------------------------------------------------------------------------
__global__ __launch_bounds__(256) void transpose_v_kernel(
    const u16* __restrict__ v, u16* __restrict__ Vt,
    int rowStride, int colOff) {
  __shared__ u16 tile[64][68];
  const int k0 = blockIdx.x * 64;
  const int d0 = blockIdx.y * 64;
  const int bk = blockIdx.z;
  const int b = bk / HKV, kvh = bk % HKV;
#pragma unroll
  for (int i = 0; i < 4; ++i) {
    int key = i * 16 + (threadIdx.x >> 4);
    int d4 = (threadIdx.x & 15) * 4;
    *reinterpret_cast<ushort2*>(&tile[key][d4]) = *reinterpret_cast<const ushort2*>(
        &v[(size_t)(b * L_ + k0 + key) * rowStride + colOff + kvh * DH + d0 + d4]);
    *reinterpret_cast<ushort2*>(&tile[key][d4 + 2]) = *reinterpret_cast<const ushort2*>(
        &v[(size_t)(b * L_ + k0 + key) * rowStride + colOff + kvh * DH + d0 + d4 + 2]);
  }
  __syncthreads();
  const int d = threadIdx.x >> 2;
  const int kq = (threadIdx.x & 3) * 16;
  u16* orow = Vt + ((size_t)(bk * DH + d0 + d)) * L_ + k0 + kq;
#pragma unroll
  for (int j = 0; j < 16; ++j) orow[j] = tile[kq + j][d];
}

// ---------------------------------------------------------------------------
// bf16 MFMA GEMM: 128x128 tile, BK=64 (half the barrier-drain count of R14),
// single-buffer, 2x __syncthreads, 2D grid. XOR-slot LDS mapping (proven
// R14): chunk = row*8 + (slot ^ (row&7)); staging source is a permutation
// within each row's 128B segment (fully coalesced); fragment reads hit
// each bank-slot exactly 2x (free). 32 MFMAs per K-step.
// ---------------------------------------------------------------------------
#define GBM 128
#define GBN 128
#define GBK 64

template <bool BF16OUT>
__global__ __launch_bounds__(256) void gemm_bf16_kernel(
    const u16* __restrict__ A, const u16* __restrict__ W,
    const float* __restrict__ bias, void* __restrict__ Cv,
    int M, int N, int K)
{
  // 1024 chunks of 16B per matrix; chunk c holds row (c>>3),
  // logical slot (c&7) ^ (row&7)   [slot = k/8 within the 64-wide K-tile]
  __shared__ u16 As[GBM * GBK];   // 16 KB
  __shared__ u16 Bs[GBN * GBK];   // 16 KB

  const int tid = threadIdx.x;
  const int wave = tid >> 6;
  const int lane = tid & 63;
  const int lr = lane & 15;
  const int lg = lane >> 4;
  const int bm = blockIdx.y * GBM;
  const int bn = blockIdx.x * GBN;
  const int wm = (wave >> 1) * 64;
  const int wn = (wave & 1) * 64;

  f32x4 acc[4][4];
#pragma unroll
  for (int i = 0; i < 4; ++i)
#pragma unroll
    for (int j = 0; j < 4; ++j) acc[i][j] = (f32x4){0.f, 0.f, 0.f, 0.f};

  // staging: thread covers chunks c = t*256 + wave*64 + lane, t = 0..3
  // (per matrix). Source row/slot from the XOR involution.
  const u16* gA[4];
  const u16* gB[4];
  u16* lA[4];
  u16* lB[4];
#pragma unroll
  for (int t = 0; t < 4; ++t) {
    int c = t * 256 + wave * 64 + lane;
    int row = c >> 3;
    int slog = (c & 7) ^ (row & 7);
    gA[t] = A + (size_t)(bm + row) * K + slog * 8;
    gB[t] = W + (size_t)(bn + row) * K + slog * 8;
    lA[t] = &As[(t * 256 + wave * 64) * 8];
    lB[t] = &Bs[(t * 256 + wave * 64) * 8];
  }

  const int fx = lr & 7;   // row&7 for fragment rows (wm/mi*16 are mult of 16)

  for (int k0 = 0; k0 < K; k0 += GBK) {
    __syncthreads();   // previous compute done before overwrite
#pragma unroll
    for (int t = 0; t < 4; ++t) {
      __builtin_amdgcn_global_load_lds(GLB(gA[t] + k0), LDS(lA[t]), 16, 0, 0);
      __builtin_amdgcn_global_load_lds(GLB(gB[t] + k0), LDS(lB[t]), 16, 0, 0);
    }
    __syncthreads();   // loads landed

#pragma unroll
    for (int kk = 0; kk < 2; ++kk) {
      short8 af[4], bf[4];
#pragma unroll
      for (int mi = 0; mi < 4; ++mi) {
        int row = wm + mi * 16 + lr;
        int slot = (kk * 4 + lg) ^ fx;
        af[mi] = *reinterpret_cast<const short8*>(&As[row * 64 + slot * 8]);
      }
#pragma unroll
      for (int ni = 0; ni < 4; ++ni) {
        int row = wn + ni * 16 + lr;
        int slot = (kk * 4 + lg) ^ fx;
        bf[ni] = *reinterpret_cast<const short8*>(&Bs[row * 64 + slot * 8]);
      }
#pragma unroll
      for (int mi = 0; mi < 4; ++mi)
#pragma unroll
        for (int ni = 0; ni < 4; ++ni)
          acc[mi][ni] = __builtin_amdgcn_mfma_f32_16x16x32_bf16(af[mi], bf[ni], acc[mi][ni], 0, 0, 0);
    }
  }

#pragma unroll
  for (int ni = 0; ni < 4; ++ni) {
    int col = bn + wn + ni * 16 + lr;
    float bv = (bias != nullptr) ? bias[col] : 0.f;
#pragma unroll
    for (int mi = 0; mi < 4; ++mi) {
#pragma unroll
      for (int r = 0; r < 4; ++r) {
        int row = bm + wm + mi * 16 + lg * 4 + r;
        float val = acc[mi][ni][r] + bv;
        if constexpr (BF16OUT)
          ((u16*)Cv)[(size_t)row * N + col] = f2bf(val);
        else
          ((float*)Cv)[(size_t)row * N + col] = val;
      }
    }
  }
}

// ---------------------------------------------------------------------------
// Flash attention, LDS K/V shared by 4 heads, counted-vmcnt pipeline (T3/T4).
// Block = 4 waves (256 thr) = 4 heads x ONE 32-row q-tile. Grid 512 = 2
// blocks/CU; blocks i and i+256 carry tiles 63-u and u (65 steps per CU).
// ---------------------------------------------------------------------------
__device__ __forceinline__ void head_step(
    const short8 qB[8], const short8 kc[8], const short8 vv[8],
    int j0, int q0, int l5, int hi, float* cbufw,
    f32x16 O[4], float& mrun, float& lrun)
{
  f32x16 accl, acch;
#pragma unroll
  for (int r = 0; r < 16; ++r) { accl[r] = 0.f; acch[r] = 0.f; }
#pragma unroll
  for (int s = 0; s < 4; ++s)
    accl = __builtin_amdgcn_mfma_f32_32x32x16_bf16(kc[s], qB[s], accl, 0, 0, 0);
#pragma unroll
  for (int s = 4; s < 8; ++s)
    acch = __builtin_amdgcn_mfma_f32_32x32x16_bf16(kc[s], qB[s], acch, 0, 0, 0);

  float S[16];
#pragma unroll
  for (int r = 0; r < 16; ++r) S[r] = accl[r] + acch[r];

  if (j0 == q0) {
#pragma unroll
    for (int r = 0; r < 16; ++r) {
      int crow = (r & 3) + 8 * (r >> 2) + 4 * hi;
      if (crow > l5) S[r] = -INFINITY;
    }
  }

  float t8[8], t4[4], t2[2];
#pragma unroll
  for (int r = 0; r < 8; ++r) t8[r] = fmaxf(S[2 * r], S[2 * r + 1]);
#pragma unroll
  for (int r = 0; r < 4; ++r) t4[r] = fmaxf(t8[2 * r], t8[2 * r + 1]);
  t2[0] = fmaxf(t4[0], t4[1]); t2[1] = fmaxf(t4[2], t4[3]);
  float pmax = fmaxf(t2[0], t2[1]);
  pmax = fmaxf(pmax, __shfl_xor(pmax, 32));

  if (__any(pmax > mrun + 8.0f)) {
    float mnew = fmaxf(mrun, pmax);
    float corr = __expf(mrun - mnew);
    mrun = mnew;
    lrun *= corr;
    if (hi == 0) cbufw[l5] = corr;
    float4 cr[4];
#pragma unroll
    for (int g = 0; g < 4; ++g)
      cr[g] = *reinterpret_cast<const float4*>(&cbufw[8 * g + 4 * hi]);
#pragma unroll
    for (int n = 0; n < 4; ++n)
#pragma unroll
      for (int r = 0; r < 16; ++r)
        O[n][r] *= (&cr[r >> 2].x)[r & 3];
  }

  float p[16];
#pragma unroll
  for (int r = 0; r < 16; ++r) p[r] = __expf(S[r] - mrun);
#pragma unroll
  for (int r = 0; r < 8; ++r) t8[r] = p[2 * r] + p[2 * r + 1];
#pragma unroll
  for (int r = 0; r < 4; ++r) t4[r] = t8[2 * r] + t8[2 * r + 1];
  t2[0] = t4[0] + t4[1]; t2[1] = t4[2] + t4[3];
  lrun += t2[0] + t2[1];

  u32 w[8];
#pragma unroll
  for (int t = 0; t < 8; ++t) w[t] = cvt_pk_bf16(p[2 * t], p[2 * t + 1]);
  permswap(w[0], w[2]); permswap(w[1], w[3]);
  permswap(w[4], w[6]); permswap(w[5], w[7]);
  short8 pa0 = __builtin_bit_cast(short8, (u32x4){w[0], w[1], w[2], w[3]});
  short8 pa1 = __builtin_bit_cast(short8, (u32x4){w[4], w[5], w[6], w[7]});

#pragma unroll
  for (int n = 0; n < 4; ++n) {
    O[n] = __builtin_amdgcn_mfma_f32_32x32x16_bf16(pa0, vv[n * 2 + 0], O[n], 0, 0, 0);
    O[n] = __builtin_amdgcn_mfma_f32_32x32x16_bf16(pa1, vv[n * 2 + 1], O[n], 0, 0, 0);
  }
}

__device__ __forceinline__ void head_epilogue(
    const f32x16 O[4], float lrun, int l5, int hi, float* cbufw,
    u16* __restrict__ obase)
{
  float ltot = lrun + __shfl_xor(lrun, 32);
  if (hi == 0) cbufw[l5] = ltot;
  float4 lv[4];
#pragma unroll
  for (int gg = 0; gg < 4; ++gg)
    lv[gg] = *reinterpret_cast<const float4*>(&cbufw[8 * gg + 4 * hi]);
#pragma unroll
  for (int r = 0; r < 16; ++r) {
    int crow = (r & 3) + 8 * (r >> 2) + 4 * hi;
    float inv = __builtin_amdgcn_rcpf((&lv[r >> 2].x)[r & 3]);
    u16* orow = obase + (size_t)crow * (HQ * DH) + l5;
#pragma unroll
    for (int n = 0; n < 4; ++n)
      orow[n * 32] = f2bf(O[n][r] * inv);
  }
}

__global__ __launch_bounds__(256, 2) void flash_attn_pipe_kernel(
    const u16* __restrict__ Qb, const u16* __restrict__ Kb,
    const u16* __restrict__ Vt, u16* __restrict__ ab)
{
  const int tid = threadIdx.x;
  const int wave = tid >> 6;
  const int lane = tid & 63;
  const int l5 = lane & 31;
  const int hi = lane >> 5;

  const int bid = blockIdx.x;
  const int half = bid >> 8;
  const int u = (bid >> 3) & 31;
  const int x = bid & 7;
  const int c = x >> 1;
  const int hh = x & 1;
  const int b = c >> 1, kvh = c & 1;
  const int h = kvh * 8 + hh * 4 + wave;
  const int t = half ? u : (63 - u);
  const int q0 = 32 * t;
  const int nst = t + 1;
  const int bk = b * HKV + kvh;

  __shared__ u16 Ks[2][32 * 128];
  __shared__ u16 Vs[2][128 * 32];
  __shared__ __align__(16) float cbuf[4][32];
  float* cbufw = cbuf[wave];

  const u16* Kg = Kb + (size_t)(b * L_) * (HKV * DH) + kvh * DH;
  const u16* Vg = Vt + (size_t)(bk * DH) * L_;

  auto stage = [&](int s) {
    const int buf = s & 1;
    const int j0 = s * 32;
#pragma unroll
    for (int q = 0; q < 2; ++q) {
      int cnk = (q * 4 + wave) * 64 + lane;
      int key = cnk >> 4, slot = cnk & 15;
      const u16* src = Kg + (size_t)(j0 + key) * (HKV * DH) + (slot ^ (key & 7)) * 8;
      __builtin_amdgcn_global_load_lds(GLB(src), LDS(&Ks[buf][(q * 4 + wave) * 64 * 8]), 16, 0, 0);
    }
#pragma unroll
    for (int q = 0; q < 2; ++q) {
      int cnk = (q * 4 + wave) * 64 + lane;
      int d = cnk >> 2, slot = cnk & 3;
      const u16* src = Vg + (size_t)d * L_ + j0 + (slot ^ ((d >> 1) & 3)) * 8;
      __builtin_amdgcn_global_load_lds(GLB(src), LDS(&Vs[buf][(q * 4 + wave) * 64 * 8]), 16, 0, 0);
    }
  };

  const u16* qrow = Qb + ((size_t)(b * L_ + q0 + l5)) * (HQ * DH) + h * DH + hi * 8;
  short8 qB[8];
#pragma unroll
  for (int ss = 0; ss < 8; ++ss)
    qB[ss] = *reinterpret_cast<const short8*>(qrow + ss * 16);

  f32x16 O[4];
#pragma unroll
  for (int n = 0; n < 4; ++n)
#pragma unroll
    for (int r = 0; r < 16; ++r) O[n][r] = 0.f;
  float mrun = -INFINITY, lrun = 0.f;

  stage(0);
  if (nst > 1) stage(1);

#pragma unroll 1
  for (int s = 0; s < nst; ++s) {
    if (s + 1 < nst) { asm volatile("s_waitcnt vmcnt(4)" ::: "memory"); }
    else             { asm volatile("s_waitcnt vmcnt(0)" ::: "memory"); }
    __builtin_amdgcn_s_barrier();
    __builtin_amdgcn_sched_barrier(0);

    const int cur = s & 1;
    short8 kc[8], vv[8];
#pragma unroll
    for (int ss = 0; ss < 8; ++ss) {
      int slot = (2 * ss + hi) ^ (l5 & 7);
      kc[ss] = *reinterpret_cast<const short8*>(&Ks[cur][l5 * 128 + slot * 8]);
    }
#pragma unroll
    for (int n = 0; n < 4; ++n) {
#pragma unroll
      for (int cc = 0; cc < 2; ++cc) {
        int d = n * 32 + l5;
        int slot = (cc * 2 + hi) ^ ((d >> 1) & 3);
        vv[n * 2 + cc] = *reinterpret_cast<const short8*>(&Vs[cur][d * 32 + slot * 8]);
      }
    }
    asm volatile("s_waitcnt lgkmcnt(0)" ::: "memory");
    __builtin_amdgcn_sched_barrier(0);
    __builtin_amdgcn_s_barrier();
    if (s + 2 < nst) stage(s + 2);

    head_step(qB, kc, vv, s * 32, q0, l5, hi, cbufw, O, mrun, lrun);
  }

  u16* obase = ab + (size_t)(b * L_ + q0) * (HQ * DH) + h * DH;
  head_epilogue(O, lrun, l5, hi, cbufw, obase);
}

// ---------------------------------------------------------------------------
// launch
// ---------------------------------------------------------------------------
extern "C" void kernel_launch(void* const* d_in, const int* in_sizes, int n_in,
                              void* d_out, int out_size, void* d_ws, size_t ws_size,
                              hipStream_t stream) {
  const float* x  = (const float*)d_in[0];
  const float* wq = (const float*)d_in[1];
  const float* wk = (const float*)d_in[2];
  const float* wv = (const float*)d_in[3];
  const float* wo = (const float*)d_in[4];
  const float* bq = (const float*)d_in[5];
  const float* bk = (const float*)d_in[6];
  const float* bv = (const float*)d_in[7];
  float* out = (float*)d_out;

  const int M = B_ * L_;
  const int NQKV = HQ * DH + 2 * HKV * DH;  // 2560
  const size_t QN = (size_t)B_ * L_ * HQ * DH;
  const size_t KN = (size_t)B_ * L_ * HKV * DH;
  const size_t TN = (size_t)L_ * (DH / 2);

  float* ws = (float*)d_ws;
  float* ct   = ws;
  float* st   = ct + TN;
  float* bqkv = st + TN;
  u16* qkvb   = (u16*)(bqkv + 2560);        // bf16 QKV projection output
  u16* xb     = qkvb + (size_t)M * NQKV;
  u16* wqkvb  = xb + (size_t)M * E_;
  u16* Qbf    = wqkvb + (size_t)NQKV * E_;
  u16* Kbf    = Qbf + QN;
  u16* Vt     = Kbf + KN;
  u16* ab     = qkvb;   // alias: qkvb dead after rope/transpose
  u16* wob    = Qbf;    // alias: Qbf dead after attention

  const float scale = 0.08838834764831845f;

  rope_tab_kernel<<<(L_ * (DH / 2) + 255) / 256, 256, 0, stream>>>(ct, st);

  cvt_bf16_kernel<<<(int)(QN / 8 / 256), 256, 0, stream>>>(x, xb, (int)QN);
  cvt_bf16_kernel<<<(HQ * DH * E_) / 8 / 256, 256, 0, stream>>>(wq, wqkvb, HQ * DH * E_);
  cvt_bf16_kernel<<<(HKV * DH * E_) / 8 / 256, 256, 0, stream>>>(
      wk, wqkvb + (size_t)(HQ * DH) * E_, HKV * DH * E_);
  cvt_bf16_kernel<<<(HKV * DH * E_) / 8 / 256, 256, 0, stream>>>(
      wv, wqkvb + (size_t)(HQ * DH + HKV * DH) * E_, HKV * DH * E_);

  hipMemcpyAsync(bqkv, bq, (size_t)HQ * DH * 4, hipMemcpyDeviceToDevice, stream);
  hipMemcpyAsync(bqkv + HQ * DH, bk, (size_t)HKV * DH * 4, hipMemcpyDeviceToDevice, stream);
  hipMemcpyAsync(bqkv + HQ * DH + HKV * DH, bv, (size_t)HKV * DH * 4, hipMemcpyDeviceToDevice, stream);

  // fused QKV projection: [4096][2560]
  gemm_bf16_kernel<true><<<dim3(NQKV / GBN, M / GBM), 256, 0, stream>>>(
      xb, wqkvb, bqkv, qkvb, M, NQKV, E_);

  {
    int totq = B_ * L_ * HQ * 64;
    rope_convert_kernel<<<(totq + 255) / 256, 256, 0, stream>>>(
        qkvb, Qbf, ct, st, HQ, NQKV, 0, scale, totq);
    int totk = B_ * L_ * HKV * 64;
    rope_convert_kernel<<<(totk + 255) / 256, 256, 0, stream>>>(
        qkvb, Kbf, ct, st, HKV, NQKV, HQ * DH, 1.0f, totk);
  }
  transpose_v_kernel<<<dim3(L_ / 64, DH / 64, B_ * HKV), 256, 0, stream>>>(
      qkvb, Vt, NQKV, HQ * DH + HKV * DH);

  flash_attn_pipe_kernel<<<dim3(512), 256, 0, stream>>>(Qbf, Kbf, Vt, ab);

  cvt_bf16_kernel<<<(E_ * E_) / 8 / 256, 256, 0, stream>>>(wo, wob, E_ * E_);
  gemm_bf16_kernel<false><<<dim3(E_ / GBN, M / GBM), 256, 0, stream>>>(
      ab, wob, nullptr, out, M, E_, E_);
}

// Round 16
// 208.730 us; speedup vs baseline: 1.6915x; 1.0353x over previous
//
#include <hip/hip_runtime.h>
#include <math.h>

#define B_ 2
#define L_ 2048
#define E_ 2048
#define HQ 16
#define HKV 2
#define DH 128

typedef unsigned short u16;
typedef unsigned int u32;
typedef __attribute__((ext_vector_type(8))) short short8;
typedef __attribute__((ext_vector_type(4))) float f32x4;
typedef __attribute__((ext_vector_type(16))) float f32x16;
typedef __attribute__((ext_vector_type(4))) u32 u32x4;

static __device__ __forceinline__ u16 f2bf(float f) {
  unsigned int u = __float_as_uint(f);
  unsigned int r = (u + 0x7fffu + ((u >> 16) & 1u)) >> 16;
  return (u16)r;
}
static __device__ __forceinline__ float bf2f(u16 v) {
  return __uint_as_float(((u32)v) << 16);
}

static __device__ __forceinline__ u32 cvt_pk_bf16(float lo, float hi) {
  u32 r;
  asm volatile("v_cvt_pk_bf16_f32 %0, %1, %2" : "=v"(r) : "v"(lo), "v"(hi));
  return r;
}
// swaps a's upper-half lanes with b's lower-half lanes (gfx950).
static __device__ __forceinline__ void permswap(u32& a, u32& b) {
  asm volatile("v_permlane32_swap_b32 %0, %1" : "+v"(a), "+v"(b));
}

#define GLB(p) ((const __attribute__((address_space(1))) void*)(p))
#define LDS(p) ((__attribute__((address_space(3))) void*)(p))

// ---------------------------------------------------------------------------
// fp32 -> bf16 convert
// ---------------------------------------------------------------------------
__global__ void cvt_bf16_kernel(const float* __restrict__ in,
                                u16* __restrict__ out, int n) {
  int i = (blockIdx.x * 256 + threadIdx.x) * 8;
  if (i >= n) return;
  float4 a = *reinterpret_cast<const float4*>(in + i);
  float4 b = *reinterpret_cast<const float4*>(in + i + 4);
  short8 r;
  r[0] = (short)f2bf(a.x); r[1] = (short)f2bf(a.y);
  r[2] = (short)f2bf(a.z); r[3] = (short)f2bf(a.w);
  r[4] = (short)f2bf(b.x); r[5] = (short)f2bf(b.y);
  r[6] = (short)f2bf(b.z); r[7] = (short)f2bf(b.w);
  *reinterpret_cast<short8*>(out + i) = r;
}

// ---------------------------------------------------------------------------
// RoPE table
// ---------------------------------------------------------------------------
__global__ void rope_tab_kernel(float* __restrict__ ctab, float* __restrict__ stab) {
  int idx = blockIdx.x * 256 + threadIdx.x;
  if (idx >= L_ * (DH / 2)) return;
  int pos = idx >> 6;
  int f = idx & 63;
  float inv_freq = powf(10000.0f, -(float)f * (1.0f / 64.0f));
  float ang = (float)pos * inv_freq;
  float s, c;
  sincosf(ang, &s, &c);
  ctab[idx] = c;
  stab[idx] = s;
}

// ---------------------------------------------------------------------------
// RoPE apply from bf16 fused-qkv buffer -> bf16 head-major buffer
// ---------------------------------------------------------------------------
__global__ void rope_convert_kernel(const u16* __restrict__ in,
                                    u16* __restrict__ outb,
                                    const float* __restrict__ ctab,
                                    const float* __restrict__ stab,
                                    int H, int rowStride, int colOff,
                                    float scale, int total) {
  int idx = blockIdx.x * 256 + threadIdx.x;
  if (idx >= total) return;
  int f = idx & 63;
  int row = idx >> 6;
  int h = row % H;
  int bl = row / H;
  int l = bl & (L_ - 1);
  size_t sbase = (size_t)bl * rowStride + colOff + (size_t)h * DH;
  size_t dbase = (size_t)bl * ((size_t)H * DH) + (size_t)h * DH;
  float x1 = bf2f(in[sbase + f]);
  float x2 = bf2f(in[sbase + 64 + f]);
  float c = ctab[l * 64 + f];
  float s = stab[l * 64 + f];
  outb[dbase + f]      = f2bf((x1 * c - x2 * s) * scale);
  outb[dbase + 64 + f] = f2bf((x2 * c + x1 * s) * scale);
}

// ---------------------------------------------------------------------------
// V transpose from bf16 qkv buffer: -> Vt[(b*HKV+kvh)*128+d][key]
// ---------------------------------------------------------------------------
__global__ __launch_bounds__(256) void transpose_v_kernel(
    const u16* __restrict__ v, u16* __restrict__ Vt,
    int rowStride, int colOff) {
  __shared__ u16 tile[64][68];
  const int k0 = blockIdx.x * 64;
  const int d0 = blockIdx.y * 64;
  const int bk = blockIdx.z;
  const int b = bk / HKV, kvh = bk % HKV;
#pragma unroll
  for (int i = 0; i < 4; ++i) {
    int key = i * 16 + (threadIdx.x >> 4);
    int d4 = (threadIdx.x & 15) * 4;
    *reinterpret_cast<ushort2*>(&tile[key][d4]) = *reinterpret_cast<const ushort2*>(
        &v[(size_t)(b * L_ + k0 + key) * rowStride + colOff + kvh * DH + d0 + d4]);
    *reinterpret_cast<ushort2*>(&tile[key][d4 + 2]) = *reinterpret_cast<const ushort2*>(
        &v[(size_t)(b * L_ + k0 + key) * rowStride + colOff + kvh * DH + d0 + d4 + 2]);
  }
  __syncthreads();
  const int d = threadIdx.x >> 2;
  const int kq = (threadIdx.x & 3) * 16;
  u16* orow = Vt + ((size_t)(bk * DH + d0 + d)) * L_ + k0 + kq;
#pragma unroll
  for (int j = 0; j < 16; ++j) orow[j] = tile[kq + j][d];
}

// ---------------------------------------------------------------------------
// bf16 MFMA GEMM: 128x128 tile, BK=64, single-buffer, 2x __syncthreads,
// XOR-slot LDS mapping (R14/R15-proven). 32 MFMAs per K-step.
// ---------------------------------------------------------------------------
#define GBM 128
#define GBN 128
#define GBK 64

template <bool BF16OUT>
__global__ __launch_bounds__(256) void gemm_bf16_kernel(
    const u16* __restrict__ A, const u16* __restrict__ W,
    const float* __restrict__ bias, void* __restrict__ Cv,
    int M, int N, int K)
{
  __shared__ u16 As[GBM * GBK];   // 16 KB
  __shared__ u16 Bs[GBN * GBK];   // 16 KB

  const int tid = threadIdx.x;
  const int wave = tid >> 6;
  const int lane = tid & 63;
  const int lr = lane & 15;
  const int lg = lane >> 4;
  const int bm = blockIdx.y * GBM;
  const int bn = blockIdx.x * GBN;
  const int wm = (wave >> 1) * 64;
  const int wn = (wave & 1) * 64;

  f32x4 acc[4][4];
#pragma unroll
  for (int i = 0; i < 4; ++i)
#pragma unroll
    for (int j = 0; j < 4; ++j) acc[i][j] = (f32x4){0.f, 0.f, 0.f, 0.f};

  const u16* gA[4];
  const u16* gB[4];
  u16* lA[4];
  u16* lB[4];
#pragma unroll
  for (int t = 0; t < 4; ++t) {
    int c = t * 256 + wave * 64 + lane;
    int row = c >> 3;
    int slog = (c & 7) ^ (row & 7);
    gA[t] = A + (size_t)(bm + row) * K + slog * 8;
    gB[t] = W + (size_t)(bn + row) * K + slog * 8;
    lA[t] = &As[(t * 256 + wave * 64) * 8];
    lB[t] = &Bs[(t * 256 + wave * 64) * 8];
  }

  const int fx = lr & 7;

  for (int k0 = 0; k0 < K; k0 += GBK) {
    __syncthreads();
#pragma unroll
    for (int t = 0; t < 4; ++t) {
      __builtin_amdgcn_global_load_lds(GLB(gA[t] + k0), LDS(lA[t]), 16, 0, 0);
      __builtin_amdgcn_global_load_lds(GLB(gB[t] + k0), LDS(lB[t]), 16, 0, 0);
    }
    __syncthreads();

#pragma unroll
    for (int kk = 0; kk < 2; ++kk) {
      short8 af[4], bf[4];
#pragma unroll
      for (int mi = 0; mi < 4; ++mi) {
        int row = wm + mi * 16 + lr;
        int slot = (kk * 4 + lg) ^ fx;
        af[mi] = *reinterpret_cast<const short8*>(&As[row * 64 + slot * 8]);
      }
#pragma unroll
      for (int ni = 0; ni < 4; ++ni) {
        int row = wn + ni * 16 + lr;
        int slot = (kk * 4 + lg) ^ fx;
        bf[ni] = *reinterpret_cast<const short8*>(&Bs[row * 64 + slot * 8]);
      }
#pragma unroll
      for (int mi = 0; mi < 4; ++mi)
#pragma unroll
        for (int ni = 0; ni < 4; ++ni)
          acc[mi][ni] = __builtin_amdgcn_mfma_f32_16x16x32_bf16(af[mi], bf[ni], acc[mi][ni], 0, 0, 0);
    }
  }

#pragma unroll
  for (int ni = 0; ni < 4; ++ni) {
    int col = bn + wn + ni * 16 + lr;
    float bv = (bias != nullptr) ? bias[col] : 0.f;
#pragma unroll
    for (int mi = 0; mi < 4; ++mi) {
#pragma unroll
      for (int r = 0; r < 4; ++r) {
        int row = bm + wm + mi * 16 + lg * 4 + r;
        float val = acc[mi][ni][r] + bv;
        if constexpr (BF16OUT)
          ((u16*)Cv)[(size_t)row * N + col] = f2bf(val);
        else
          ((float*)Cv)[(size_t)row * N + col] = val;
      }
    }
  }
}

// ---------------------------------------------------------------------------
// Flash attention, KVBLK=64 (two 32-key subtiles per step), LDS K/V shared
// by 4 heads, counted-vmcnt pipeline. Block = 4 waves = 4 heads x ONE 32-row
// q-tile; grid 512 = 2 blocks/CU (blocks i, i+256 carry tiles 63-u and u).
// Critical path: 32 steps (vs 64 at KVBLK=32) — halves per-step fixed cost.
// ---------------------------------------------------------------------------
__device__ __forceinline__ void pack16(const float p[16], short8& pa0, short8& pa1) {
  u32 w[8];
#pragma unroll
  for (int t = 0; t < 8; ++t) w[t] = cvt_pk_bf16(p[2 * t], p[2 * t + 1]);
  permswap(w[0], w[2]); permswap(w[1], w[3]);
  permswap(w[4], w[6]); permswap(w[5], w[7]);
  pa0 = __builtin_bit_cast(short8, (u32x4){w[0], w[1], w[2], w[3]});
  pa1 = __builtin_bit_cast(short8, (u32x4){w[4], w[5], w[6], w[7]});
}

__device__ __forceinline__ void head_epilogue(
    const f32x16 O[4], float lrun, int l5, int hi, float* cbufw,
    u16* __restrict__ obase)
{
  float ltot = lrun + __shfl_xor(lrun, 32);
  if (hi == 0) cbufw[l5] = ltot;
  float4 lv[4];
#pragma unroll
  for (int gg = 0; gg < 4; ++gg)
    lv[gg] = *reinterpret_cast<const float4*>(&cbufw[8 * gg + 4 * hi]);
#pragma unroll
  for (int r = 0; r < 16; ++r) {
    int crow = (r & 3) + 8 * (r >> 2) + 4 * hi;
    float inv = __builtin_amdgcn_rcpf((&lv[r >> 2].x)[r & 3]);
    u16* orow = obase + (size_t)crow * (HQ * DH) + l5;
#pragma unroll
    for (int n = 0; n < 4; ++n)
      orow[n * 32] = f2bf(O[n][r] * inv);
  }
}

__global__ __launch_bounds__(256, 2) void flash_attn_pipe_kernel(
    const u16* __restrict__ Qb, const u16* __restrict__ Kb,
    const u16* __restrict__ Vt, u16* __restrict__ ab)
{
  const int tid = threadIdx.x;
  const int wave = tid >> 6;
  const int lane = tid & 63;
  const int l5 = lane & 31;
  const int hi = lane >> 5;

  const int bid = blockIdx.x;
  const int half = bid >> 8;
  const int u = (bid >> 3) & 31;
  const int x = bid & 7;
  const int c = x >> 1;
  const int hh = x & 1;
  const int b = c >> 1, kvh = c & 1;
  const int h = kvh * 8 + hh * 4 + wave;
  const int t = half ? u : (63 - u);
  const int q0 = 32 * t;
  const int nst = (t + 2) >> 1;          // 64-key steps
  const int bk = b * HKV + kvh;

  __shared__ u16 Ks[2][64 * 128];   // 32 KB; 16 slots/row, phys = slot^(key&15)
  __shared__ u16 Vs[2][128 * 64];   // 32 KB; 8 slots/row,  phys = slot^(d&7)
  __shared__ __align__(16) float cbuf[4][32];
  float* cbufw = cbuf[wave];

  const u16* Kg = Kb + (size_t)(b * L_) * (HKV * DH) + kvh * DH;
  const u16* Vg = Vt + (size_t)(bk * DH) * L_;

  // 8 global_load_lds per thread per stage (4 K + 4 V chunks)
  auto stage = [&](int s) {
    const int buf = s & 1;
    const int j0 = s * 64;
#pragma unroll
    for (int q = 0; q < 4; ++q) {
      int cnk = q * 256 + tid;            // K chunk 0..1023
      int key = cnk >> 4, phys = cnk & 15;
      int slog = phys ^ (key & 15);
      const u16* src = Kg + (size_t)(j0 + key) * (HKV * DH) + slog * 8;
      __builtin_amdgcn_global_load_lds(GLB(src), LDS(&Ks[buf][(q * 256 + wave * 64) * 8]), 16, 0, 0);
    }
#pragma unroll
    for (int q = 0; q < 4; ++q) {
      int cnk = q * 256 + tid;            // V chunk 0..1023
      int d = cnk >> 3, phys = cnk & 7;
      int slog = phys ^ (d & 7);
      const u16* src = Vg + (size_t)d * L_ + j0 + slog * 8;
      __builtin_amdgcn_global_load_lds(GLB(src), LDS(&Vs[buf][(q * 256 + wave * 64) * 8]), 16, 0, 0);
    }
  };

  const u16* qrow = Qb + ((size_t)(b * L_ + q0 + l5)) * (HQ * DH) + h * DH + hi * 8;
  short8 qB[8];
#pragma unroll
  for (int ss = 0; ss < 8; ++ss)
    qB[ss] = *reinterpret_cast<const short8*>(qrow + ss * 16);

  f32x16 O[4];
#pragma unroll
  for (int n = 0; n < 4; ++n)
#pragma unroll
    for (int r = 0; r < 16; ++r) O[n][r] = 0.f;
  float mrun = -INFINITY, lrun = 0.f;

  stage(0);
  if (nst > 1) stage(1);

#pragma unroll 1
  for (int s = 0; s < nst; ++s) {
    if (s + 1 < nst) { asm volatile("s_waitcnt vmcnt(8)" ::: "memory"); }
    else             { asm volatile("s_waitcnt vmcnt(0)" ::: "memory"); }
    __builtin_amdgcn_s_barrier();          // buf[s&1] landed for all waves
    __builtin_amdgcn_sched_barrier(0);

    const int cur = s & 1;
    const int j0 = s * 64;
    const int kx = l5 & 15;

    // subtile A: keys j0 + 0..31
    short8 kcA[8], vvA[8];
#pragma unroll
    for (int ss = 0; ss < 8; ++ss) {
      int phys = (2 * ss + hi) ^ kx;
      kcA[ss] = *reinterpret_cast<const short8*>(&Ks[cur][l5 * 128 + phys * 8]);
    }
#pragma unroll
    for (int n = 0; n < 4; ++n) {
#pragma unroll
      for (int cc = 0; cc < 2; ++cc) {
        int d = n * 32 + l5;
        int phys = (cc * 2 + hi) ^ (d & 7);
        vvA[n * 2 + cc] = *reinterpret_cast<const short8*>(&Vs[cur][d * 64 + phys * 8]);
      }
    }
    f32x16 Sa;
#pragma unroll
    for (int r = 0; r < 16; ++r) Sa[r] = 0.f;
#pragma unroll
    for (int ss = 0; ss < 8; ++ss)
      Sa = __builtin_amdgcn_mfma_f32_32x32x16_bf16(kcA[ss], qB[ss], Sa, 0, 0, 0);

    // subtile B: keys j0 + 32..63
    short8 kcB[8], vvB[8];
#pragma unroll
    for (int ss = 0; ss < 8; ++ss) {
      int phys = (2 * ss + hi) ^ kx;
      kcB[ss] = *reinterpret_cast<const short8*>(&Ks[cur][(32 + l5) * 128 + phys * 8]);
    }
#pragma unroll
    for (int n = 0; n < 4; ++n) {
#pragma unroll
      for (int cc = 0; cc < 2; ++cc) {
        int d = n * 32 + l5;
        int phys = (4 + cc * 2 + hi) ^ (d & 7);
        vvB[n * 2 + cc] = *reinterpret_cast<const short8*>(&Vs[cur][d * 64 + phys * 8]);
      }
    }
    f32x16 Sb;
#pragma unroll
    for (int r = 0; r < 16; ++r) Sb[r] = 0.f;
#pragma unroll
    for (int ss = 0; ss < 8; ++ss)
      Sb = __builtin_amdgcn_mfma_f32_32x32x16_bf16(kcB[ss], qB[ss], Sb, 0, 0, 0);

    asm volatile("s_waitcnt lgkmcnt(0)" ::: "memory");
    __builtin_amdgcn_sched_barrier(0);
    __builtin_amdgcn_s_barrier();          // all waves done reading buf[cur]
    if (s + 2 < nst) stage(s + 2);         // overwrite buf[cur] for step s+2

    float sa[16], sb[16];
#pragma unroll
    for (int r = 0; r < 16; ++r) { sa[r] = Sa[r]; sb[r] = Sb[r]; }

    // causal masks
    if (j0 == q0) {
#pragma unroll
      for (int r = 0; r < 16; ++r) {
        int crow = (r & 3) + 8 * (r >> 2) + 4 * hi;
        if (crow > l5) sa[r] = -INFINITY;
        sb[r] = -INFINITY;                 // keys q0+32.. all beyond queries
      }
    } else if (j0 + 32 == q0) {
#pragma unroll
      for (int r = 0; r < 16; ++r) {
        int crow = (r & 3) + 8 * (r >> 2) + 4 * hi;
        if (crow > l5) sb[r] = -INFINITY;
      }
    }

    // row max over 64 keys: in-register trees + one cross-half exchange
    float t8[8], t4[4];
#pragma unroll
    for (int r = 0; r < 8; ++r) t8[r] = fmaxf(fmaxf(sa[2 * r], sa[2 * r + 1]),
                                              fmaxf(sb[2 * r], sb[2 * r + 1]));
#pragma unroll
    for (int r = 0; r < 4; ++r) t4[r] = fmaxf(t8[2 * r], t8[2 * r + 1]);
    float pmax = fmaxf(fmaxf(t4[0], t4[1]), fmaxf(t4[2], t4[3]));
    pmax = fmaxf(pmax, __shfl_xor(pmax, 32));

    // defer-max rescale (T13)
    if (__any(pmax > mrun + 8.0f)) {
      float mnew = fmaxf(mrun, pmax);
      float corr = __expf(mrun - mnew);
      mrun = mnew;
      lrun *= corr;
      if (hi == 0) cbufw[l5] = corr;
      float4 cr[4];
#pragma unroll
      for (int g = 0; g < 4; ++g)
        cr[g] = *reinterpret_cast<const float4*>(&cbufw[8 * g + 4 * hi]);
#pragma unroll
      for (int n = 0; n < 4; ++n)
#pragma unroll
        for (int r = 0; r < 16; ++r)
          O[n][r] *= (&cr[r >> 2].x)[r & 3];
    }

    // P = exp(S - m); per-half partial sum (cross-half merge at epilogue)
    float pa_[16], pb_[16];
#pragma unroll
    for (int r = 0; r < 16; ++r) {
      pa_[r] = __expf(sa[r] - mrun);
      pb_[r] = __expf(sb[r] - mrun);
    }
#pragma unroll
    for (int r = 0; r < 8; ++r) t8[r] = (pa_[2 * r] + pa_[2 * r + 1]) +
                                        (pb_[2 * r] + pb_[2 * r + 1]);
#pragma unroll
    for (int r = 0; r < 4; ++r) t4[r] = t8[2 * r] + t8[2 * r + 1];
    lrun += (t4[0] + t4[1]) + (t4[2] + t4[3]);

    // pack P -> A-fragments (T12, R5-validated per 16-value group)
    short8 paA0, paA1, paB0, paB1;
    pack16(pa_, paA0, paA1);
    pack16(pb_, paB0, paB1);

    // O += P V (4 k-slots of 16)
#pragma unroll
    for (int n = 0; n < 4; ++n) {
      O[n] = __builtin_amdgcn_mfma_f32_32x32x16_bf16(paA0, vvA[n * 2 + 0], O[n], 0, 0, 0);
      O[n] = __builtin_amdgcn_mfma_f32_32x32x16_bf16(paA1, vvA[n * 2 + 1], O[n], 0, 0, 0);
      O[n] = __builtin_amdgcn_mfma_f32_32x32x16_bf16(paB0, vvB[n * 2 + 0], O[n], 0, 0, 0);
      O[n] = __builtin_amdgcn_mfma_f32_32x32x16_bf16(paB1, vvB[n * 2 + 1], O[n], 0, 0, 0);
    }
  }

  u16* obase = ab + (size_t)(b * L_ + q0) * (HQ * DH) + h * DH;
  head_epilogue(O, lrun, l5, hi, cbufw, obase);
}

// ---------------------------------------------------------------------------
// launch
// ---------------------------------------------------------------------------
extern "C" void kernel_launch(void* const* d_in, const int* in_sizes, int n_in,
                              void* d_out, int out_size, void* d_ws, size_t ws_size,
                              hipStream_t stream) {
  const float* x  = (const float*)d_in[0];
  const float* wq = (const float*)d_in[1];
  const float* wk = (const float*)d_in[2];
  const float* wv = (const float*)d_in[3];
  const float* wo = (const float*)d_in[4];
  const float* bq = (const float*)d_in[5];
  const float* bk = (const float*)d_in[6];
  const float* bv = (const float*)d_in[7];
  float* out = (float*)d_out;

  const int M = B_ * L_;
  const int NQKV = HQ * DH + 2 * HKV * DH;  // 2560
  const size_t QN = (size_t)B_ * L_ * HQ * DH;
  const size_t KN = (size_t)B_ * L_ * HKV * DH;
  const size_t TN = (size_t)L_ * (DH / 2);

  float* ws = (float*)d_ws;
  float* ct   = ws;
  float* st   = ct + TN;
  float* bqkv = st + TN;
  u16* qkvb   = (u16*)(bqkv + 2560);        // bf16 QKV projection output
  u16* xb     = qkvb + (size_t)M * NQKV;
  u16* wqkvb  = xb + (size_t)M * E_;
  u16* Qbf    = wqkvb + (size_t)NQKV * E_;
  u16* Kbf    = Qbf + QN;
  u16* Vt     = Kbf + KN;
  u16* ab     = qkvb;   // alias: qkvb dead after rope/transpose
  u16* wob    = Qbf;    // alias: Qbf dead after attention

  const float scale = 0.08838834764831845f;

  rope_tab_kernel<<<(L_ * (DH / 2) + 255) / 256, 256, 0, stream>>>(ct, st);

  cvt_bf16_kernel<<<(int)(QN / 8 / 256), 256, 0, stream>>>(x, xb, (int)QN);
  cvt_bf16_kernel<<<(HQ * DH * E_) / 8 / 256, 256, 0, stream>>>(wq, wqkvb, HQ * DH * E_);
  cvt_bf16_kernel<<<(HKV * DH * E_) / 8 / 256, 256, 0, stream>>>(
      wk, wqkvb + (size_t)(HQ * DH) * E_, HKV * DH * E_);
  cvt_bf16_kernel<<<(HKV * DH * E_) / 8 / 256, 256, 0, stream>>>(
      wv, wqkvb + (size_t)(HQ * DH + HKV * DH) * E_, HKV * DH * E_);

  hipMemcpyAsync(bqkv, bq, (size_t)HQ * DH * 4, hipMemcpyDeviceToDevice, stream);
  hipMemcpyAsync(bqkv + HQ * DH, bk, (size_t)HKV * DH * 4, hipMemcpyDeviceToDevice, stream);
  hipMemcpyAsync(bqkv + HQ * DH + HKV * DH, bv, (size_t)HKV * DH * 4, hipMemcpyDeviceToDevice, stream);

  // fused QKV projection: [4096][2560]
  gemm_bf16_kernel<true><<<dim3(NQKV / GBN, M / GBM), 256, 0, stream>>>(
      xb, wqkvb, bqkv, qkvb, M, NQKV, E_);

  {
    int totq = B_ * L_ * HQ * 64;
    rope_convert_kernel<<<(totq + 255) / 256, 256, 0, stream>>>(
        qkvb, Qbf, ct, st, HQ, NQKV, 0, scale, totq);
    int totk = B_ * L_ * HKV * 64;
    rope_convert_kernel<<<(totk + 255) / 256, 256, 0, stream>>>(
        qkvb, Kbf, ct, st, HKV, NQKV, HQ * DH, 1.0f, totk);
  }
  transpose_v_kernel<<<dim3(L_ / 64, DH / 64, B_ * HKV), 256, 0, stream>>>(
      qkvb, Vt, NQKV, HQ * DH + HKV * DH);

  flash_attn_pipe_kernel<<<dim3(512), 256, 0, stream>>>(Qbf, Kbf, Vt, ab);

  cvt_bf16_kernel<<<(E_ * E_) / 8 / 256, 256, 0, stream>>>(wo, wob, E_ * E_);
  gemm_bf16_kernel<false><<<dim3(E_ / GBN, M / GBM), 256, 0, stream>>>(
      ab, wob, nullptr, out, M, E_, E_);
}